// Round 9
// baseline (263.147 us; speedup 1.0000x reference)
//
#include <hip/hip_runtime.h>

#define NN 50000
#define NE 500000
#define FIN 16
#define FOUT 16
#define HID 64
#define TROW 1040   // (HID+1)*16 elems per node: j=0..63 = W2 part, j=64 = b2 part

typedef unsigned int  uint;
typedef unsigned short ushort;

__device__ __forceinline__ ushort f2bf(float f) {   // RNE f32->bf16
    uint u = __float_as_uint(f);
    u += 0x7fffu + ((u >> 16) & 1u);
    return (ushort)(u >> 16);
}
__device__ __forceinline__ float bflo(uint u) { return __uint_as_float(u << 16); }
__device__ __forceinline__ float bfhi(uint u) { return __uint_as_float(u & 0xffff0000u); }

// ===========================================================================
// MAIN PATH. Round-8 lesson: edge kernel invariant at 80us across ILP/occ
// configs -> scalar-pipe bound (1024 stride-256B s_loads of W1 per edge,
// SGPR=48 = no prefetch). Fix: W1T[j][16] contiguous -> wide s_load_dwordx16;
// chunked h/T phases; atomic moved out of edge kernel (pos_d from count).
// ===========================================================================

// W2R[j][o][i] = W2[j][i*16+o] (j<64), b2[i*16+o] (j==64); W1T[j][i]=W1[i][j]
__global__ __launch_bounds__(256) void w2r_prep(
    const float* __restrict__ W2, const float* __restrict__ b2,
    const float* __restrict__ W1, float* __restrict__ W2R,
    float* __restrict__ W1T)
{
    const int t = blockIdx.x * blockDim.x + threadIdx.x;
    if (t < 64 * 16) {
        const int j = t >> 4, i = t & 15;
        W1T[t] = W1[i * HID + j];
    }
    if (t >= 65 * 256) return;
    const int j = t >> 8;
    const int col = t & 255;          // col = i*16 + o
    const int i = col >> 4, o = col & 15;
    const float v = (j < 64) ? W2[j * 256 + col] : b2[col];
    W2R[j * 256 + o * 16 + i] = v;    // [j][o][i]
}

// one pass: src ranks (for src-sort), dst ranks (for direct slot write),
// and both degree histograms.
__global__ __launch_bounds__(256) void count_both(
    const int* __restrict__ src, const int* __restrict__ dst,
    int* __restrict__ deg_s, int* __restrict__ pos_s,
    int* __restrict__ deg_d, int* __restrict__ pos_d)
{
    const int e = blockIdx.x * blockDim.x + threadIdx.x;
    if (e >= NE) return;
    pos_s[e] = atomicAdd(deg_s + src[e], 1);
    pos_d[e] = atomicAdd(deg_d + dst[e], 1);
}

// two independent exclusive scans (block 0: A, block 1: B), n=NN each
__global__ __launch_bounds__(1024) void dgc_scan2(
    const int* __restrict__ degA, int* __restrict__ offA,
    const int* __restrict__ degB, int* __restrict__ offB)
{
    const int* __restrict__ deg = blockIdx.x ? degB : degA;
    int* __restrict__ offs      = blockIdx.x ? offB : offA;
    __shared__ int wsum[16];
    const int tid = threadIdx.x;
    const int lane = tid & 63;
    const int wid = tid >> 6;
    int carry = 0;
    for (int base = 0; base < NN; base += 1024) {
        const int idx = base + tid;
        const int v = (idx < NN) ? deg[idx] : 0;
        int s = v;
        #pragma unroll
        for (int d = 1; d < 64; d <<= 1) {
            int t = __shfl_up(s, d, 64);
            if (lane >= d) s += t;
        }
        if (lane == 63) wsum[wid] = s;
        __syncthreads();
        if (wid == 0 && lane < 16) {
            int w = wsum[lane];
            #pragma unroll
            for (int d = 1; d < 16; d <<= 1) {
                int t = __shfl_up(w, d, 64);
                if (lane >= d) w += t;
            }
            wsum[lane] = w;
        }
        __syncthreads();
        const int wpre = (wid == 0) ? 0 : wsum[wid - 1];
        if (idx < NN) offs[idx] = carry + wpre + (s - v);
        carry += wsum[15];
        __syncthreads();
    }
    if (tid == 0) offs[NN] = carry;
}

__global__ __launch_bounds__(256) void scatter_src(
    const int* __restrict__ src, const int* __restrict__ pos_s,
    const int* __restrict__ offs_s, int* __restrict__ eidx_s)
{
    const int e = blockIdx.x * blockDim.x + threadIdx.x;
    if (e >= NE) return;
    eidx_s[offs_s[src[e]] + pos_s[e]] = e;
}

// tprep5 (round-8 proven): thread (jt,o) owns W2R rows {jt,jt+16,jt+32,jt+48}
// in 64 f32 regs; grid-stride nodes; coalesced 2B stores; no LDS.
__global__ __launch_bounds__(256) void tprep5(
    const float* __restrict__ x, const float* __restrict__ W2R,
    ushort* __restrict__ T)
{
    const int tid = threadIdx.x;
    const int jt = tid >> 4, o = tid & 15;

    float w0[16], w1[16], w2[16], w3[16];
    {
        const float4* p0 = reinterpret_cast<const float4*>(W2R + (jt     ) * 256 + o * 16);
        const float4* p1 = reinterpret_cast<const float4*>(W2R + (jt + 16) * 256 + o * 16);
        const float4* p2 = reinterpret_cast<const float4*>(W2R + (jt + 32) * 256 + o * 16);
        const float4* p3 = reinterpret_cast<const float4*>(W2R + (jt + 48) * 256 + o * 16);
        #pragma unroll
        for (int q = 0; q < 4; ++q) {
            float4 a = p0[q]; w0[4*q]=a.x; w0[4*q+1]=a.y; w0[4*q+2]=a.z; w0[4*q+3]=a.w;
            float4 b = p1[q]; w1[4*q]=b.x; w1[4*q+1]=b.y; w1[4*q+2]=b.z; w1[4*q+3]=b.w;
            float4 c = p2[q]; w2[4*q]=c.x; w2[4*q+1]=c.y; w2[4*q+2]=c.z; w2[4*q+3]=c.w;
            float4 d = p3[q]; w3[4*q]=d.x; w3[4*q+1]=d.y; w3[4*q+2]=d.z; w3[4*q+3]=d.w;
        }
    }
    float wb[16];
    if (jt == 0) {
        const float4* pb = reinterpret_cast<const float4*>(W2R + 64 * 256 + o * 16);
        #pragma unroll
        for (int q = 0; q < 4; ++q) {
            float4 a = pb[q]; wb[4*q]=a.x; wb[4*q+1]=a.y; wb[4*q+2]=a.z; wb[4*q+3]=a.w;
        }
    }

    for (int n = blockIdx.x; n < NN; n += gridDim.x) {
        float xr[16];
        {
            const float4* p = reinterpret_cast<const float4*>(x) + (size_t)n * 4;
            float4 a = p[0], b = p[1], c = p[2], d = p[3];
            xr[0]=a.x; xr[1]=a.y; xr[2]=a.z;  xr[3]=a.w;
            xr[4]=b.x; xr[5]=b.y; xr[6]=b.z;  xr[7]=b.w;
            xr[8]=c.x; xr[9]=c.y; xr[10]=c.z; xr[11]=c.w;
            xr[12]=d.x; xr[13]=d.y; xr[14]=d.z; xr[15]=d.w;
        }
        ushort* tw = T + (size_t)n * TROW;

        float s0 = xr[0]*w0[0], s1 = xr[0]*w1[0], s2 = xr[0]*w2[0], s3 = xr[0]*w3[0];
        #pragma unroll
        for (int i = 1; i < 16; ++i) {
            s0 = fmaf(xr[i], w0[i], s0);
            s1 = fmaf(xr[i], w1[i], s1);
            s2 = fmaf(xr[i], w2[i], s2);
            s3 = fmaf(xr[i], w3[i], s3);
        }
        tw[tid]       = f2bf(s0);
        tw[tid + 256] = f2bf(s1);
        tw[tid + 512] = f2bf(s2);
        tw[tid + 768] = f2bf(s3);
        if (jt == 0) {
            float sb = xr[0]*wb[0];
            #pragma unroll
            for (int i = 1; i < 16; ++i) sb = fmaf(xr[i], wb[i], sb);
            tw[1024 + o] = f2bf(sb);
        }
    }
}

// edge_msg4: 1 edge/thread; 4 chunks of 16 j: {hh[16] from W1T (wide s_load)
// -> T-sweep}. No atomics (pos_d precomputed). Direct dst-slot write.
__global__ __launch_bounds__(256) void edge_msg4(
    const int* __restrict__ eidx_s, const int* __restrict__ src,
    const int* __restrict__ dst, const float* __restrict__ ef,
    const float* __restrict__ W1T, const float* __restrict__ b1,
    const ushort* __restrict__ T, const int* __restrict__ offs_d,
    const int* __restrict__ pos_d, float* __restrict__ msgbuf)
{
    const int k = blockIdx.x * blockDim.x + threadIdx.x;
    if (k >= NE) return;
    const int e = eidx_s[k];
    const int s = src[e];

    float efv[16];
    {
        const float4* p = reinterpret_cast<const float4*>(ef) + (size_t)e * 4;
        float4 a = p[0], b = p[1], c = p[2], d = p[3];
        efv[0]=a.x; efv[1]=a.y; efv[2]=a.z;  efv[3]=a.w;
        efv[4]=b.x; efv[5]=b.y; efv[6]=b.z;  efv[7]=b.w;
        efv[8]=c.x; efv[9]=c.y; efv[10]=c.z; efv[11]=c.w;
        efv[12]=d.x; efv[13]=d.y; efv[14]=d.z; efv[15]=d.w;
    }

    const ushort* tr = T + (size_t)s * TROW;
    float m[16];
    {   // b2 row: j=64 -> ushort offset 1024
        uint4 a = *reinterpret_cast<const uint4*>(tr + 1024);
        uint4 b = *reinterpret_cast<const uint4*>(tr + 1032);
        m[0]=bflo(a.x);  m[1]=bfhi(a.x);  m[2]=bflo(a.y);  m[3]=bfhi(a.y);
        m[4]=bflo(a.z);  m[5]=bfhi(a.z);  m[6]=bflo(a.w);  m[7]=bfhi(a.w);
        m[8]=bflo(b.x);  m[9]=bfhi(b.x);  m[10]=bflo(b.y); m[11]=bfhi(b.y);
        m[12]=bflo(b.z); m[13]=bfhi(b.z); m[14]=bflo(b.w); m[15]=bfhi(b.w);
    }

    for (int jc = 0; jc < 4; ++jc) {          // rolled: 6.5KB body, I$-resident
        const float*  wc = W1T + jc * 256;    // 16 contiguous rows of 16 (uniform)
        const float*  bc = b1 + jc * 16;      // uniform
        const ushort* tc = tr + jc * 256;

        float hh[16];
        #pragma unroll
        for (int jj = 0; jj < 16; ++jj) {
            float hj = bc[jj];
            #pragma unroll
            for (int i = 0; i < 16; ++i)
                hj = fmaf(efv[i], wc[jj * 16 + i], hj);
            hh[jj] = fmaxf(hj, 0.f);
        }

        #pragma unroll
        for (int jj = 0; jj < 16; ++jj) {
            const float h = hh[jj];
            uint4 a = *reinterpret_cast<const uint4*>(tc + jj * 16);
            uint4 b = *reinterpret_cast<const uint4*>(tc + jj * 16 + 8);
            m[0]  = fmaf(h, bflo(a.x), m[0]);  m[1]  = fmaf(h, bfhi(a.x), m[1]);
            m[2]  = fmaf(h, bflo(a.y), m[2]);  m[3]  = fmaf(h, bfhi(a.y), m[3]);
            m[4]  = fmaf(h, bflo(a.z), m[4]);  m[5]  = fmaf(h, bfhi(a.z), m[5]);
            m[6]  = fmaf(h, bflo(a.w), m[6]);  m[7]  = fmaf(h, bfhi(a.w), m[7]);
            m[8]  = fmaf(h, bflo(b.x), m[8]);  m[9]  = fmaf(h, bfhi(b.x), m[9]);
            m[10] = fmaf(h, bflo(b.y), m[10]); m[11] = fmaf(h, bfhi(b.y), m[11]);
            m[12] = fmaf(h, bflo(b.z), m[12]); m[13] = fmaf(h, bfhi(b.z), m[13]);
            m[14] = fmaf(h, bflo(b.w), m[14]); m[15] = fmaf(h, bfhi(b.w), m[15]);
        }
    }

    const int d = dst[e];
    const int slot = offs_d[d] + pos_d[e];
    float4* mr = reinterpret_cast<float4*>(msgbuf + (size_t)slot * 16);
    mr[0] = make_float4(m[0], m[1], m[2], m[3]);
    mr[1] = make_float4(m[4], m[5], m[6], m[7]);
    mr[2] = make_float4(m[8], m[9], m[10], m[11]);
    mr[3] = make_float4(m[12], m[13], m[14], m[15]);
}

// contiguous-range gather: 16 lanes per node stream deg*64B
__global__ __launch_bounds__(256) void gather_mean2(
    const float* __restrict__ msgbuf, const int* __restrict__ offs_d,
    const float* __restrict__ x, const float* __restrict__ bias,
    float* __restrict__ out)
{
    const int t = blockIdx.x * blockDim.x + threadIdx.x;
    if (t >= NN * FOUT) return;
    const int n = t >> 4;
    const int o = t & 15;
    const int beg = offs_d[n], end = offs_d[n + 1];
    float s = 0.f;
    for (int k = beg; k < end; ++k)
        s += msgbuf[(size_t)k * 16 + o];
    const int d = end - beg;
    const float v = (d > 0) ? (s / (float)d) : x[t];
    out[t] = v + bias[o];
}

// ===========================================================================
// FALLBACK (round-2 proven path, ~36.4 MB ws)
// ===========================================================================
__global__ __launch_bounds__(1024) void dgc_scan(
    const int* __restrict__ deg, int* __restrict__ offs, int n)
{
    __shared__ int wsum[16];
    const int tid = threadIdx.x;
    const int lane = tid & 63;
    const int wid = tid >> 6;
    int carry = 0;
    for (int base = 0; base < n; base += 1024) {
        const int idx = base + tid;
        const int v = (idx < n) ? deg[idx] : 0;
        int s = v;
        #pragma unroll
        for (int d = 1; d < 64; d <<= 1) {
            int t = __shfl_up(s, d, 64);
            if (lane >= d) s += t;
        }
        if (lane == 63) wsum[wid] = s;
        __syncthreads();
        if (wid == 0 && lane < 16) {
            int w = wsum[lane];
            #pragma unroll
            for (int d = 1; d < 16; d <<= 1) {
                int t = __shfl_up(w, d, 64);
                if (lane >= d) w += t;
            }
            wsum[lane] = w;
        }
        __syncthreads();
        const int wpre = (wid == 0) ? 0 : wsum[wid - 1];
        if (idx < n) offs[idx] = carry + wpre + (s - v);
        carry += wsum[15];
        __syncthreads();
    }
    if (tid == 0) offs[n] = carry;
}

__global__ __launch_bounds__(256) void dgc_edge_csr(
    const float* __restrict__ x, const float* __restrict__ ef,
    const int* __restrict__ src, const int* __restrict__ dst,
    const float* __restrict__ W1, const float* __restrict__ b1,
    const float* __restrict__ W2, const float* __restrict__ b2,
    float* __restrict__ msg, int* __restrict__ pos, int* __restrict__ deg)
{
    const int e = blockIdx.x * blockDim.x + threadIdx.x;
    if (e >= NE) return;
    float efv[16];
    {
        const float4* p = reinterpret_cast<const float4*>(ef) + (size_t)e * 4;
        float4 a = p[0], b = p[1], c = p[2], d = p[3];
        efv[0]=a.x; efv[1]=a.y; efv[2]=a.z;  efv[3]=a.w;
        efv[4]=b.x; efv[5]=b.y; efv[6]=b.z;  efv[7]=b.w;
        efv[8]=c.x; efv[9]=c.y; efv[10]=c.z; efv[11]=c.w;
        efv[12]=d.x; efv[13]=d.y; efv[14]=d.z; efv[15]=d.w;
    }
    const int s = src[e];
    float xs[16];
    {
        const float4* p = reinterpret_cast<const float4*>(x) + (size_t)s * 4;
        float4 a = p[0], b = p[1], c = p[2], d = p[3];
        xs[0]=a.x; xs[1]=a.y; xs[2]=a.z;  xs[3]=a.w;
        xs[4]=b.x; xs[5]=b.y; xs[6]=b.z;  xs[7]=b.w;
        xs[8]=c.x; xs[9]=c.y; xs[10]=c.z; xs[11]=c.w;
        xs[12]=d.x; xs[13]=d.y; xs[14]=d.z; xs[15]=d.w;
    }
    float m[16];
    #pragma unroll
    for (int o = 0; o < 16; ++o) m[o] = 0.f;
    #pragma unroll
    for (int i = 0; i < 16; ++i) {
        const float xi = xs[i];
        #pragma unroll
        for (int o = 0; o < 16; ++o) m[o] = fmaf(xi, b2[i * 16 + o], m[o]);
    }
    for (int j = 0; j < HID; ++j) {
        float hj = b1[j];
        #pragma unroll
        for (int i = 0; i < 16; ++i) hj = fmaf(efv[i], W1[i * HID + j], hj);
        hj = fmaxf(hj, 0.f);
        const float* __restrict__ w2r = W2 + (size_t)j * 256;
        float t[16];
        #pragma unroll
        for (int o = 0; o < 16; ++o) t[o] = 0.f;
        #pragma unroll
        for (int i = 0; i < 16; ++i) {
            const float xi = xs[i];
            #pragma unroll
            for (int o = 0; o < 16; ++o) t[o] = fmaf(xi, w2r[i * 16 + o], t[o]);
        }
        #pragma unroll
        for (int o = 0; o < 16; ++o) m[o] = fmaf(hj, t[o], m[o]);
    }
    float4* mr = reinterpret_cast<float4*>(msg + (size_t)e * 16);
    mr[0] = make_float4(m[0], m[1], m[2], m[3]);
    mr[1] = make_float4(m[4], m[5], m[6], m[7]);
    mr[2] = make_float4(m[8], m[9], m[10], m[11]);
    mr[3] = make_float4(m[12], m[13], m[14], m[15]);
    pos[e] = atomicAdd(deg + dst[e], 1);
}

__global__ __launch_bounds__(256) void dgc_scatter(
    const int* __restrict__ dst, const int* __restrict__ pos,
    const int* __restrict__ offs, int* __restrict__ eidx)
{
    const int e = blockIdx.x * blockDim.x + threadIdx.x;
    if (e >= NE) return;
    eidx[offs[dst[e]] + pos[e]] = e;
}

__global__ __launch_bounds__(256) void dgc_gather(
    const float* __restrict__ msg, const int* __restrict__ offs,
    const int* __restrict__ eidx, const float* __restrict__ x,
    const float* __restrict__ bias, float* __restrict__ out)
{
    const int t = blockIdx.x * blockDim.x + threadIdx.x;
    if (t >= NN * FOUT) return;
    const int n = t >> 4;
    const int o = t & 15;
    const int beg = offs[n], end = offs[n + 1];
    float s = 0.f;
    for (int k = beg; k < end; ++k)
        s += msg[(size_t)eidx[k] * 16 + o];
    const int d = end - beg;
    const float v = (d > 0) ? (s / (float)d) : x[t];
    out[t] = v + bias[o];
}

extern "C" void kernel_launch(void* const* d_in, const int* in_sizes, int n_in,
                              void* d_out, int out_size, void* d_ws, size_t ws_size,
                              hipStream_t stream) {
    const float* x    = (const float*)d_in[0];
    const float* ef   = (const float*)d_in[1];
    const int*   src  = (const int*)d_in[2];
    const int*   dst  = (const int*)d_in[3];
    const float* W1   = (const float*)d_in[4];
    const float* b1   = (const float*)d_in[5];
    const float* W2   = (const float*)d_in[6];
    const float* b2   = (const float*)d_in[7];
    const float* bias = (const float*)d_in[8];
    float* out = (float*)d_out;

    // main-path ws layout
    ushort* T      = (ushort*)d_ws;                       // NN*TROW bf16 (104 MB)
    float*  msgbuf = (float*)(T + (size_t)NN * TROW);     // NE*16 f32   (32 MB)
    float*  W2R    = msgbuf + (size_t)NE * 16;            // 65*256
    float*  W1T    = W2R + 65 * 256;                      // 64*16
    int*    deg_s  = (int*)(W1T + 64 * 16);               // NN
    int*    deg_d  = deg_s + NN;                          // NN
    int*    offs_s = deg_d + NN;                          // NN+1
    int*    offs_d = offs_s + NN + 1;                     // NN+1
    int*    pos_s  = offs_d + NN + 1;                     // NE
    int*    pos_d  = pos_s + NE;                          // NE
    int*    eidx_s = pos_d + NE;                          // NE
    const size_t needed =
        (size_t)NN * TROW * 2 +
        ((size_t)NE * 16 + 65 * 256 + 64 * 16) * 4 +
        ((size_t)2 * NN + 2 * (NN + 1) + (size_t)3 * NE) * 4;

    if (ws_size >= needed) {
        hipMemsetAsync(deg_s, 0, (size_t)2 * NN * sizeof(int), stream);  // deg_s,deg_d
        w2r_prep<<<(65 * 256 + 255) / 256, 256, 0, stream>>>(W2, b2, W1, W2R, W1T);
        count_both<<<(NE + 255) / 256, 256, 0, stream>>>(src, dst, deg_s, pos_s, deg_d, pos_d);
        dgc_scan2<<<2, 1024, 0, stream>>>(deg_s, offs_s, deg_d, offs_d);
        scatter_src<<<(NE + 255) / 256, 256, 0, stream>>>(src, pos_s, offs_s, eidx_s);
        tprep5<<<2048, 256, 0, stream>>>(x, W2R, T);
        edge_msg4<<<(NE + 255) / 256, 256, 0, stream>>>(
            eidx_s, src, dst, ef, W1T, b1, T, offs_d, pos_d, msgbuf);
        gather_mean2<<<(NN * FOUT + 255) / 256, 256, 0, stream>>>(
            msgbuf, offs_d, x, bias, out);
    } else {
        // round-2 fallback
        float* msg  = (float*)d_ws;
        int*   deg  = (int*)(msg + (size_t)NE * 16);
        int*   offs = deg + NN;
        int*   pos  = offs + NN + 1;
        int*   eidx = pos + NE;
        hipMemsetAsync(deg, 0, (size_t)NN * sizeof(int), stream);
        dgc_edge_csr<<<(NE + 255) / 256, 256, 0, stream>>>(
            x, ef, src, dst, W1, b1, W2, b2, msg, pos, deg);
        dgc_scan<<<1, 1024, 0, stream>>>(deg, offs, NN);
        dgc_scatter<<<(NE + 255) / 256, 256, 0, stream>>>(dst, pos, offs, eidx);
        dgc_gather<<<(NN * FOUT + 255) / 256, 256, 0, stream>>>(
            msg, offs, eidx, x, bias, out);
    }
}

// Round 10
// 220.012 us; speedup vs baseline: 1.1961x; 1.1961x over previous
//
#include <hip/hip_runtime.h>

#define NN 50000
#define NE 500000
#define FIN 16
#define FOUT 16
#define HID 64
#define TROW 1040   // (HID+1)*16 elems per node: j=0..63 = W2 part, j=64 = b2 part

typedef unsigned int  uint;
typedef unsigned short ushort;

__device__ __forceinline__ ushort f2bf(float f) {   // RNE f32->bf16
    uint u = __float_as_uint(f);
    u += 0x7fffu + ((u >> 16) & 1u);
    return (ushort)(u >> 16);
}
__device__ __forceinline__ float bflo(uint u) { return __uint_as_float(u << 16); }
__device__ __forceinline__ float bfhi(uint u) { return __uint_as_float(u & 0xffff0000u); }

// ===========================================================================
// MAIN PATH. Round-9 lesson: hh-chunking raised VGPR 56->116, occ 20%, -40%.
// Edge kernel reverted to r8's proven 80us shape (VGPR 56), atomic removed
// (pos_d precomputed in count pass). Machinery merged 7->4 kernels to cut
// the ~55us of inter-dispatch gaps (r8: sum(kernels)=175 vs total 233).
// ===========================================================================

// blocks [0,1954): count ranks+degrees. blocks [1954,+65): W2R/W1T transforms.
__global__ __launch_bounds__(256) void count_w2r(
    const int* __restrict__ src, const int* __restrict__ dst,
    int* __restrict__ deg_s, int* __restrict__ pos_s,
    int* __restrict__ deg_d, int* __restrict__ pos_d,
    const float* __restrict__ W2, const float* __restrict__ b2,
    const float* __restrict__ W1, float* __restrict__ W2R,
    float* __restrict__ W1T)
{
    const int nbc = (NE + 255) / 256;
    if ((int)blockIdx.x < nbc) {
        const int e = blockIdx.x * 256 + threadIdx.x;
        if (e < NE) {
            pos_s[e] = atomicAdd(deg_s + src[e], 1);
            pos_d[e] = atomicAdd(deg_d + dst[e], 1);
        }
    } else {
        const int t = (blockIdx.x - nbc) * 256 + threadIdx.x;
        if (t < 64 * 16) {
            const int j = t >> 4, i = t & 15;
            W1T[t] = W1[i * HID + j];          // W1T[j][i] = W1[i][j]
        }
        if (t < 65 * 256) {
            const int j = t >> 8;
            const int col = t & 255;           // col = i*16 + o
            const int i = col >> 4, o = col & 15;
            const float v = (j < 64) ? W2[j * 256 + col] : b2[col];
            W2R[j * 256 + o * 16 + i] = v;     // W2R[j][o][i]
        }
    }
}

// two independent exclusive scans (block 0: A, block 1: B), n=NN each
__global__ __launch_bounds__(1024) void dgc_scan2(
    const int* __restrict__ degA, int* __restrict__ offA,
    const int* __restrict__ degB, int* __restrict__ offB)
{
    const int* __restrict__ deg = blockIdx.x ? degB : degA;
    int* __restrict__ offs      = blockIdx.x ? offB : offA;
    __shared__ int wsum[16];
    const int tid = threadIdx.x;
    const int lane = tid & 63;
    const int wid = tid >> 6;
    int carry = 0;
    for (int base = 0; base < NN; base += 1024) {
        const int idx = base + tid;
        const int v = (idx < NN) ? deg[idx] : 0;
        int s = v;
        #pragma unroll
        for (int d = 1; d < 64; d <<= 1) {
            int t = __shfl_up(s, d, 64);
            if (lane >= d) s += t;
        }
        if (lane == 63) wsum[wid] = s;
        __syncthreads();
        if (wid == 0 && lane < 16) {
            int w = wsum[lane];
            #pragma unroll
            for (int d = 1; d < 16; d <<= 1) {
                int t = __shfl_up(w, d, 64);
                if (lane >= d) w += t;
            }
            wsum[lane] = w;
        }
        __syncthreads();
        const int wpre = (wid == 0) ? 0 : wsum[wid - 1];
        if (idx < NN) offs[idx] = carry + wpre + (s - v);
        carry += wsum[15];
        __syncthreads();
    }
    if (tid == 0) offs[NN] = carry;
}

// blocks [0,1954): scatter edge ids into src-CSR. blocks [1954,+2048): tprep5
// (thread (jt,o) owns 4 W2R rows in regs; grid-stride nodes; coalesced stores).
__global__ __launch_bounds__(256) void scatter_tprep(
    const int* __restrict__ src, const int* __restrict__ pos_s,
    const int* __restrict__ offs_s, int* __restrict__ eidx_s,
    const float* __restrict__ x, const float* __restrict__ W2R,
    ushort* __restrict__ T)
{
    const int nbs = (NE + 255) / 256;
    if ((int)blockIdx.x < nbs) {
        const int e = blockIdx.x * 256 + threadIdx.x;
        if (e < NE) eidx_s[offs_s[src[e]] + pos_s[e]] = e;
        return;
    }
    const int bid = blockIdx.x - nbs;      // 0..2047
    const int tid = threadIdx.x;
    const int jt = tid >> 4, o = tid & 15;

    float w0[16], w1[16], w2[16], w3[16];
    {
        const float4* p0 = reinterpret_cast<const float4*>(W2R + (jt     ) * 256 + o * 16);
        const float4* p1 = reinterpret_cast<const float4*>(W2R + (jt + 16) * 256 + o * 16);
        const float4* p2 = reinterpret_cast<const float4*>(W2R + (jt + 32) * 256 + o * 16);
        const float4* p3 = reinterpret_cast<const float4*>(W2R + (jt + 48) * 256 + o * 16);
        #pragma unroll
        for (int q = 0; q < 4; ++q) {
            float4 a = p0[q]; w0[4*q]=a.x; w0[4*q+1]=a.y; w0[4*q+2]=a.z; w0[4*q+3]=a.w;
            float4 b = p1[q]; w1[4*q]=b.x; w1[4*q+1]=b.y; w1[4*q+2]=b.z; w1[4*q+3]=b.w;
            float4 c = p2[q]; w2[4*q]=c.x; w2[4*q+1]=c.y; w2[4*q+2]=c.z; w2[4*q+3]=c.w;
            float4 d = p3[q]; w3[4*q]=d.x; w3[4*q+1]=d.y; w3[4*q+2]=d.z; w3[4*q+3]=d.w;
        }
    }
    float wb[16];
    if (jt == 0) {
        const float4* pb = reinterpret_cast<const float4*>(W2R + 64 * 256 + o * 16);
        #pragma unroll
        for (int q = 0; q < 4; ++q) {
            float4 a = pb[q]; wb[4*q]=a.x; wb[4*q+1]=a.y; wb[4*q+2]=a.z; wb[4*q+3]=a.w;
        }
    }

    for (int n = bid; n < NN; n += 2048) {
        float xr[16];
        {
            const float4* p = reinterpret_cast<const float4*>(x) + (size_t)n * 4;
            float4 a = p[0], b = p[1], c = p[2], d = p[3];
            xr[0]=a.x; xr[1]=a.y; xr[2]=a.z;  xr[3]=a.w;
            xr[4]=b.x; xr[5]=b.y; xr[6]=b.z;  xr[7]=b.w;
            xr[8]=c.x; xr[9]=c.y; xr[10]=c.z; xr[11]=c.w;
            xr[12]=d.x; xr[13]=d.y; xr[14]=d.z; xr[15]=d.w;
        }
        ushort* tw = T + (size_t)n * TROW;

        float s0 = xr[0]*w0[0], s1 = xr[0]*w1[0], s2 = xr[0]*w2[0], s3 = xr[0]*w3[0];
        #pragma unroll
        for (int i = 1; i < 16; ++i) {
            s0 = fmaf(xr[i], w0[i], s0);
            s1 = fmaf(xr[i], w1[i], s1);
            s2 = fmaf(xr[i], w2[i], s2);
            s3 = fmaf(xr[i], w3[i], s3);
        }
        tw[tid]       = f2bf(s0);
        tw[tid + 256] = f2bf(s1);
        tw[tid + 512] = f2bf(s2);
        tw[tid + 768] = f2bf(s3);
        if (jt == 0) {
            float sb = xr[0]*wb[0];
            #pragma unroll
            for (int i = 1; i < 16; ++i) sb = fmaf(xr[i], wb[i], sb);
            tw[1024 + o] = f2bf(sb);
        }
    }
}

// edge_msg3 (r8 proven 80us shape): two consecutive src-sorted slots per
// thread (2x ILP; shared-src T lines L1-hit). No atomics (pos_d precomputed).
__global__ __launch_bounds__(256) void edge_msg3(
    const int* __restrict__ eidx_s, const int* __restrict__ src,
    const int* __restrict__ dst, const float* __restrict__ ef,
    const float* __restrict__ W1, const float* __restrict__ b1,
    const ushort* __restrict__ T, const int* __restrict__ offs_d,
    const int* __restrict__ pos_d, float* __restrict__ msgbuf)
{
    const int k0 = (blockIdx.x * blockDim.x + threadIdx.x) * 2;
    if (k0 >= NE) return;
    const bool two = (k0 + 1 < NE);
    const int k1 = two ? (k0 + 1) : k0;

    const int e0 = eidx_s[k0], e1 = eidx_s[k1];
    const int s0 = src[e0],    s1 = src[e1];

    float ea[16], eb[16];
    {
        const float4* p = reinterpret_cast<const float4*>(ef) + (size_t)e0 * 4;
        float4 a = p[0], b = p[1], c = p[2], d = p[3];
        ea[0]=a.x; ea[1]=a.y; ea[2]=a.z;  ea[3]=a.w;
        ea[4]=b.x; ea[5]=b.y; ea[6]=b.z;  ea[7]=b.w;
        ea[8]=c.x; ea[9]=c.y; ea[10]=c.z; ea[11]=c.w;
        ea[12]=d.x; ea[13]=d.y; ea[14]=d.z; ea[15]=d.w;
    }
    {
        const float4* p = reinterpret_cast<const float4*>(ef) + (size_t)e1 * 4;
        float4 a = p[0], b = p[1], c = p[2], d = p[3];
        eb[0]=a.x; eb[1]=a.y; eb[2]=a.z;  eb[3]=a.w;
        eb[4]=b.x; eb[5]=b.y; eb[6]=b.z;  eb[7]=b.w;
        eb[8]=c.x; eb[9]=c.y; eb[10]=c.z; eb[11]=c.w;
        eb[12]=d.x; eb[13]=d.y; eb[14]=d.z; eb[15]=d.w;
    }

    const ushort* tr0 = T + (size_t)s0 * TROW;
    const ushort* tr1 = T + (size_t)s1 * TROW;

    float m0[16], m1[16];
    {
        uint4 a = *reinterpret_cast<const uint4*>(tr0 + 1024);
        uint4 b = *reinterpret_cast<const uint4*>(tr0 + 1032);
        m0[0]=bflo(a.x);  m0[1]=bfhi(a.x);  m0[2]=bflo(a.y);  m0[3]=bfhi(a.y);
        m0[4]=bflo(a.z);  m0[5]=bfhi(a.z);  m0[6]=bflo(a.w);  m0[7]=bfhi(a.w);
        m0[8]=bflo(b.x);  m0[9]=bfhi(b.x);  m0[10]=bflo(b.y); m0[11]=bfhi(b.y);
        m0[12]=bflo(b.z); m0[13]=bfhi(b.z); m0[14]=bflo(b.w); m0[15]=bfhi(b.w);
    }
    {
        uint4 a = *reinterpret_cast<const uint4*>(tr1 + 1024);
        uint4 b = *reinterpret_cast<const uint4*>(tr1 + 1032);
        m1[0]=bflo(a.x);  m1[1]=bfhi(a.x);  m1[2]=bflo(a.y);  m1[3]=bfhi(a.y);
        m1[4]=bflo(a.z);  m1[5]=bfhi(a.z);  m1[6]=bflo(a.w);  m1[7]=bfhi(a.w);
        m1[8]=bflo(b.x);  m1[9]=bfhi(b.x);  m1[10]=bflo(b.y); m1[11]=bfhi(b.y);
        m1[12]=bflo(b.z); m1[13]=bfhi(b.z); m1[14]=bflo(b.w); m1[15]=bfhi(b.w);
    }

    for (int j = 0; j < HID; ++j) {
        float h0 = b1[j], h1 = h0;
        #pragma unroll
        for (int i = 0; i < 16; ++i) {
            const float w = W1[i * HID + j];
            h0 = fmaf(ea[i], w, h0);
            h1 = fmaf(eb[i], w, h1);
        }
        h0 = fmaxf(h0, 0.f);
        h1 = fmaxf(h1, 0.f);

        uint4 a0 = *reinterpret_cast<const uint4*>(tr0 + j * 16);
        uint4 b0 = *reinterpret_cast<const uint4*>(tr0 + j * 16 + 8);
        uint4 a1 = *reinterpret_cast<const uint4*>(tr1 + j * 16);
        uint4 b1v = *reinterpret_cast<const uint4*>(tr1 + j * 16 + 8);
        m0[0]  = fmaf(h0, bflo(a0.x), m0[0]);  m0[1]  = fmaf(h0, bfhi(a0.x), m0[1]);
        m0[2]  = fmaf(h0, bflo(a0.y), m0[2]);  m0[3]  = fmaf(h0, bfhi(a0.y), m0[3]);
        m0[4]  = fmaf(h0, bflo(a0.z), m0[4]);  m0[5]  = fmaf(h0, bfhi(a0.z), m0[5]);
        m0[6]  = fmaf(h0, bflo(a0.w), m0[6]);  m0[7]  = fmaf(h0, bfhi(a0.w), m0[7]);
        m0[8]  = fmaf(h0, bflo(b0.x), m0[8]);  m0[9]  = fmaf(h0, bfhi(b0.x), m0[9]);
        m0[10] = fmaf(h0, bflo(b0.y), m0[10]); m0[11] = fmaf(h0, bfhi(b0.y), m0[11]);
        m0[12] = fmaf(h0, bflo(b0.z), m0[12]); m0[13] = fmaf(h0, bfhi(b0.z), m0[13]);
        m0[14] = fmaf(h0, bflo(b0.w), m0[14]); m0[15] = fmaf(h0, bfhi(b0.w), m0[15]);
        m1[0]  = fmaf(h1, bflo(a1.x), m1[0]);  m1[1]  = fmaf(h1, bfhi(a1.x), m1[1]);
        m1[2]  = fmaf(h1, bflo(a1.y), m1[2]);  m1[3]  = fmaf(h1, bfhi(a1.y), m1[3]);
        m1[4]  = fmaf(h1, bflo(a1.z), m1[4]);  m1[5]  = fmaf(h1, bfhi(a1.z), m1[5]);
        m1[6]  = fmaf(h1, bflo(a1.w), m1[6]);  m1[7]  = fmaf(h1, bfhi(a1.w), m1[7]);
        m1[8]  = fmaf(h1, bflo(b1v.x), m1[8]);  m1[9]  = fmaf(h1, bfhi(b1v.x), m1[9]);
        m1[10] = fmaf(h1, bflo(b1v.y), m1[10]); m1[11] = fmaf(h1, bfhi(b1v.y), m1[11]);
        m1[12] = fmaf(h1, bflo(b1v.z), m1[12]); m1[13] = fmaf(h1, bfhi(b1v.z), m1[13]);
        m1[14] = fmaf(h1, bflo(b1v.w), m1[14]); m1[15] = fmaf(h1, bfhi(b1v.w), m1[15]);
    }

    {
        const int d = dst[e0];
        const int slot = offs_d[d] + pos_d[e0];
        float4* mr = reinterpret_cast<float4*>(msgbuf + (size_t)slot * 16);
        mr[0] = make_float4(m0[0], m0[1], m0[2], m0[3]);
        mr[1] = make_float4(m0[4], m0[5], m0[6], m0[7]);
        mr[2] = make_float4(m0[8], m0[9], m0[10], m0[11]);
        mr[3] = make_float4(m0[12], m0[13], m0[14], m0[15]);
    }
    if (two) {
        const int d = dst[e1];
        const int slot = offs_d[d] + pos_d[e1];
        float4* mr = reinterpret_cast<float4*>(msgbuf + (size_t)slot * 16);
        mr[0] = make_float4(m1[0], m1[1], m1[2], m1[3]);
        mr[1] = make_float4(m1[4], m1[5], m1[6], m1[7]);
        mr[2] = make_float4(m1[8], m1[9], m1[10], m1[11]);
        mr[3] = make_float4(m1[12], m1[13], m1[14], m1[15]);
    }
}

// contiguous-range gather: 16 lanes per node stream deg*64B
__global__ __launch_bounds__(256) void gather_mean2(
    const float* __restrict__ msgbuf, const int* __restrict__ offs_d,
    const float* __restrict__ x, const float* __restrict__ bias,
    float* __restrict__ out)
{
    const int t = blockIdx.x * blockDim.x + threadIdx.x;
    if (t >= NN * FOUT) return;
    const int n = t >> 4;
    const int o = t & 15;
    const int beg = offs_d[n], end = offs_d[n + 1];
    float s = 0.f;
    for (int k = beg; k < end; ++k)
        s += msgbuf[(size_t)k * 16 + o];
    const int d = end - beg;
    const float v = (d > 0) ? (s / (float)d) : x[t];
    out[t] = v + bias[o];
}

// ===========================================================================
// FALLBACK (round-2 proven path, ~36.4 MB ws)
// ===========================================================================
__global__ __launch_bounds__(1024) void dgc_scan(
    const int* __restrict__ deg, int* __restrict__ offs, int n)
{
    __shared__ int wsum[16];
    const int tid = threadIdx.x;
    const int lane = tid & 63;
    const int wid = tid >> 6;
    int carry = 0;
    for (int base = 0; base < n; base += 1024) {
        const int idx = base + tid;
        const int v = (idx < n) ? deg[idx] : 0;
        int s = v;
        #pragma unroll
        for (int d = 1; d < 64; d <<= 1) {
            int t = __shfl_up(s, d, 64);
            if (lane >= d) s += t;
        }
        if (lane == 63) wsum[wid] = s;
        __syncthreads();
        if (wid == 0 && lane < 16) {
            int w = wsum[lane];
            #pragma unroll
            for (int d = 1; d < 16; d <<= 1) {
                int t = __shfl_up(w, d, 64);
                if (lane >= d) w += t;
            }
            wsum[lane] = w;
        }
        __syncthreads();
        const int wpre = (wid == 0) ? 0 : wsum[wid - 1];
        if (idx < n) offs[idx] = carry + wpre + (s - v);
        carry += wsum[15];
        __syncthreads();
    }
    if (tid == 0) offs[n] = carry;
}

__global__ __launch_bounds__(256) void dgc_edge_csr(
    const float* __restrict__ x, const float* __restrict__ ef,
    const int* __restrict__ src, const int* __restrict__ dst,
    const float* __restrict__ W1, const float* __restrict__ b1,
    const float* __restrict__ W2, const float* __restrict__ b2,
    float* __restrict__ msg, int* __restrict__ pos, int* __restrict__ deg)
{
    const int e = blockIdx.x * blockDim.x + threadIdx.x;
    if (e >= NE) return;
    float efv[16];
    {
        const float4* p = reinterpret_cast<const float4*>(ef) + (size_t)e * 4;
        float4 a = p[0], b = p[1], c = p[2], d = p[3];
        efv[0]=a.x; efv[1]=a.y; efv[2]=a.z;  efv[3]=a.w;
        efv[4]=b.x; efv[5]=b.y; efv[6]=b.z;  efv[7]=b.w;
        efv[8]=c.x; efv[9]=c.y; efv[10]=c.z; efv[11]=c.w;
        efv[12]=d.x; efv[13]=d.y; efv[14]=d.z; efv[15]=d.w;
    }
    const int s = src[e];
    float xs[16];
    {
        const float4* p = reinterpret_cast<const float4*>(x) + (size_t)s * 4;
        float4 a = p[0], b = p[1], c = p[2], d = p[3];
        xs[0]=a.x; xs[1]=a.y; xs[2]=a.z;  xs[3]=a.w;
        xs[4]=b.x; xs[5]=b.y; xs[6]=b.z;  xs[7]=b.w;
        xs[8]=c.x; xs[9]=c.y; xs[10]=c.z; xs[11]=c.w;
        xs[12]=d.x; xs[13]=d.y; xs[14]=d.z; xs[15]=d.w;
    }
    float m[16];
    #pragma unroll
    for (int o = 0; o < 16; ++o) m[o] = 0.f;
    #pragma unroll
    for (int i = 0; i < 16; ++i) {
        const float xi = xs[i];
        #pragma unroll
        for (int o = 0; o < 16; ++o) m[o] = fmaf(xi, b2[i * 16 + o], m[o]);
    }
    for (int j = 0; j < HID; ++j) {
        float hj = b1[j];
        #pragma unroll
        for (int i = 0; i < 16; ++i) hj = fmaf(efv[i], W1[i * HID + j], hj);
        hj = fmaxf(hj, 0.f);
        const float* __restrict__ w2r = W2 + (size_t)j * 256;
        float t[16];
        #pragma unroll
        for (int o = 0; o < 16; ++o) t[o] = 0.f;
        #pragma unroll
        for (int i = 0; i < 16; ++i) {
            const float xi = xs[i];
            #pragma unroll
            for (int o = 0; o < 16; ++o) t[o] = fmaf(xi, w2r[i * 16 + o], t[o]);
        }
        #pragma unroll
        for (int o = 0; o < 16; ++o) m[o] = fmaf(hj, t[o], m[o]);
    }
    float4* mr = reinterpret_cast<float4*>(msg + (size_t)e * 16);
    mr[0] = make_float4(m[0], m[1], m[2], m[3]);
    mr[1] = make_float4(m[4], m[5], m[6], m[7]);
    mr[2] = make_float4(m[8], m[9], m[10], m[11]);
    mr[3] = make_float4(m[12], m[13], m[14], m[15]);
    pos[e] = atomicAdd(deg + dst[e], 1);
}

__global__ __launch_bounds__(256) void dgc_scatter(
    const int* __restrict__ dst, const int* __restrict__ pos,
    const int* __restrict__ offs, int* __restrict__ eidx)
{
    const int e = blockIdx.x * blockDim.x + threadIdx.x;
    if (e >= NE) return;
    eidx[offs[dst[e]] + pos[e]] = e;
}

__global__ __launch_bounds__(256) void dgc_gather(
    const float* __restrict__ msg, const int* __restrict__ offs,
    const int* __restrict__ eidx, const float* __restrict__ x,
    const float* __restrict__ bias, float* __restrict__ out)
{
    const int t = blockIdx.x * blockDim.x + threadIdx.x;
    if (t >= NN * FOUT) return;
    const int n = t >> 4;
    const int o = t & 15;
    const int beg = offs[n], end = offs[n + 1];
    float s = 0.f;
    for (int k = beg; k < end; ++k)
        s += msg[(size_t)eidx[k] * 16 + o];
    const int d = end - beg;
    const float v = (d > 0) ? (s / (float)d) : x[t];
    out[t] = v + bias[o];
}

extern "C" void kernel_launch(void* const* d_in, const int* in_sizes, int n_in,
                              void* d_out, int out_size, void* d_ws, size_t ws_size,
                              hipStream_t stream) {
    const float* x    = (const float*)d_in[0];
    const float* ef   = (const float*)d_in[1];
    const int*   src  = (const int*)d_in[2];
    const int*   dst  = (const int*)d_in[3];
    const float* W1   = (const float*)d_in[4];
    const float* b1   = (const float*)d_in[5];
    const float* W2   = (const float*)d_in[6];
    const float* b2   = (const float*)d_in[7];
    const float* bias = (const float*)d_in[8];
    float* out = (float*)d_out;

    // main-path ws layout
    ushort* T      = (ushort*)d_ws;                       // NN*TROW bf16 (104 MB)
    float*  msgbuf = (float*)(T + (size_t)NN * TROW);     // NE*16 f32   (32 MB)
    float*  W2R    = msgbuf + (size_t)NE * 16;            // 65*256
    float*  W1T    = W2R + 65 * 256;                      // 64*16
    int*    deg_s  = (int*)(W1T + 64 * 16);               // NN
    int*    deg_d  = deg_s + NN;                          // NN
    int*    offs_s = deg_d + NN;                          // NN+1
    int*    offs_d = offs_s + NN + 1;                     // NN+1
    int*    pos_s  = offs_d + NN + 1;                     // NE
    int*    pos_d  = pos_s + NE;                          // NE
    int*    eidx_s = pos_d + NE;                          // NE
    const size_t needed =
        (size_t)NN * TROW * 2 +
        ((size_t)NE * 16 + 65 * 256 + 64 * 16) * 4 +
        ((size_t)2 * NN + 2 * (NN + 1) + (size_t)3 * NE) * 4;

    const int nbc = (NE + 255) / 256;   // 1954

    if (ws_size >= needed) {
        hipMemsetAsync(deg_s, 0, (size_t)2 * NN * sizeof(int), stream);
        count_w2r<<<nbc + 65, 256, 0, stream>>>(
            src, dst, deg_s, pos_s, deg_d, pos_d, W2, b2, W1, W2R, W1T);
        dgc_scan2<<<2, 1024, 0, stream>>>(deg_s, offs_s, deg_d, offs_d);
        scatter_tprep<<<nbc + 2048, 256, 0, stream>>>(
            src, pos_s, offs_s, eidx_s, x, W2R, T);
        edge_msg3<<<(NE / 2 + 255) / 256, 256, 0, stream>>>(
            eidx_s, src, dst, ef, W1, b1, T, offs_d, pos_d, msgbuf);
        gather_mean2<<<(NN * FOUT + 255) / 256, 256, 0, stream>>>(
            msgbuf, offs_d, x, bias, out);
    } else {
        // round-2 fallback
        float* msg  = (float*)d_ws;
        int*   deg  = (int*)(msg + (size_t)NE * 16);
        int*   offs = deg + NN;
        int*   pos  = offs + NN + 1;
        int*   eidx = pos + NE;
        hipMemsetAsync(deg, 0, (size_t)NN * sizeof(int), stream);
        dgc_edge_csr<<<(NE + 255) / 256, 256, 0, stream>>>(
            x, ef, src, dst, W1, b1, W2, b2, msg, pos, deg);
        dgc_scan<<<1, 1024, 0, stream>>>(deg, offs, NN);
        dgc_scatter<<<(NE + 255) / 256, 256, 0, stream>>>(dst, pos, offs, eidx);
        dgc_gather<<<(NN * FOUT + 255) / 256, 256, 0, stream>>>(
            msg, offs, eidx, x, bias, out);
    }
}

// Round 11
// 216.540 us; speedup vs baseline: 1.2152x; 1.0160x over previous
//
#include <hip/hip_runtime.h>

#define NN 50000
#define NE 500000
#define FIN 16
#define FOUT 16
#define HID 64
#define TROW 1040   // (HID+1)*16 elems per node: j=0..63 = W2 part, j=64 = b2 part

typedef unsigned int  uint;
typedef unsigned short ushort;

__device__ __forceinline__ ushort f2bf(float f) {   // RNE f32->bf16
    uint u = __float_as_uint(f);
    u += 0x7fffu + ((u >> 16) & 1u);
    return (ushort)(u >> 16);
}
__device__ __forceinline__ float bflo(uint u) { return __uint_as_float(u << 16); }
__device__ __forceinline__ float bfhi(uint u) { return __uint_as_float(u & 0xffff0000u); }

// ===========================================================================
// MAIN PATH. Round-10: 220us. Round-11 changes (minimal, per r9 lesson that
// restructuring costs VGPR): (1) edge_msg3 reads W1T rows (contiguous 64B ->
// one s_load_dwordx16 per j instead of 16 stride-256B s_loads; VGPR-neutral);
// (2) gather vectorized float4 (4 outputs/thread, 4x fewer load instrs).
// ===========================================================================

// blocks [0,1954): count ranks+degrees. blocks [1954,+65): W2R/W1T transforms.
__global__ __launch_bounds__(256) void count_w2r(
    const int* __restrict__ src, const int* __restrict__ dst,
    int* __restrict__ deg_s, int* __restrict__ pos_s,
    int* __restrict__ deg_d, int* __restrict__ pos_d,
    const float* __restrict__ W2, const float* __restrict__ b2,
    const float* __restrict__ W1, float* __restrict__ W2R,
    float* __restrict__ W1T)
{
    const int nbc = (NE + 255) / 256;
    if ((int)blockIdx.x < nbc) {
        const int e = blockIdx.x * 256 + threadIdx.x;
        if (e < NE) {
            pos_s[e] = atomicAdd(deg_s + src[e], 1);
            pos_d[e] = atomicAdd(deg_d + dst[e], 1);
        }
    } else {
        const int t = (blockIdx.x - nbc) * 256 + threadIdx.x;
        if (t < 64 * 16) {
            const int j = t >> 4, i = t & 15;
            W1T[t] = W1[i * HID + j];          // W1T[j][i] = W1[i][j]
        }
        if (t < 65 * 256) {
            const int j = t >> 8;
            const int col = t & 255;           // col = i*16 + o
            const int i = col >> 4, o = col & 15;
            const float v = (j < 64) ? W2[j * 256 + col] : b2[col];
            W2R[j * 256 + o * 16 + i] = v;     // W2R[j][o][i]
        }
    }
}

// two independent exclusive scans (block 0: A, block 1: B), n=NN each
__global__ __launch_bounds__(1024) void dgc_scan2(
    const int* __restrict__ degA, int* __restrict__ offA,
    const int* __restrict__ degB, int* __restrict__ offB)
{
    const int* __restrict__ deg = blockIdx.x ? degB : degA;
    int* __restrict__ offs      = blockIdx.x ? offB : offA;
    __shared__ int wsum[16];
    const int tid = threadIdx.x;
    const int lane = tid & 63;
    const int wid = tid >> 6;
    int carry = 0;
    for (int base = 0; base < NN; base += 1024) {
        const int idx = base + tid;
        const int v = (idx < NN) ? deg[idx] : 0;
        int s = v;
        #pragma unroll
        for (int d = 1; d < 64; d <<= 1) {
            int t = __shfl_up(s, d, 64);
            if (lane >= d) s += t;
        }
        if (lane == 63) wsum[wid] = s;
        __syncthreads();
        if (wid == 0 && lane < 16) {
            int w = wsum[lane];
            #pragma unroll
            for (int d = 1; d < 16; d <<= 1) {
                int t = __shfl_up(w, d, 64);
                if (lane >= d) w += t;
            }
            wsum[lane] = w;
        }
        __syncthreads();
        const int wpre = (wid == 0) ? 0 : wsum[wid - 1];
        if (idx < NN) offs[idx] = carry + wpre + (s - v);
        carry += wsum[15];
        __syncthreads();
    }
    if (tid == 0) offs[NN] = carry;
}

// blocks [0,1954): scatter edge ids into src-CSR. blocks [1954,+2048): tprep5.
__global__ __launch_bounds__(256) void scatter_tprep(
    const int* __restrict__ src, const int* __restrict__ pos_s,
    const int* __restrict__ offs_s, int* __restrict__ eidx_s,
    const float* __restrict__ x, const float* __restrict__ W2R,
    ushort* __restrict__ T)
{
    const int nbs = (NE + 255) / 256;
    if ((int)blockIdx.x < nbs) {
        const int e = blockIdx.x * 256 + threadIdx.x;
        if (e < NE) eidx_s[offs_s[src[e]] + pos_s[e]] = e;
        return;
    }
    const int bid = blockIdx.x - nbs;      // 0..2047
    const int tid = threadIdx.x;
    const int jt = tid >> 4, o = tid & 15;

    float w0[16], w1[16], w2[16], w3[16];
    {
        const float4* p0 = reinterpret_cast<const float4*>(W2R + (jt     ) * 256 + o * 16);
        const float4* p1 = reinterpret_cast<const float4*>(W2R + (jt + 16) * 256 + o * 16);
        const float4* p2 = reinterpret_cast<const float4*>(W2R + (jt + 32) * 256 + o * 16);
        const float4* p3 = reinterpret_cast<const float4*>(W2R + (jt + 48) * 256 + o * 16);
        #pragma unroll
        for (int q = 0; q < 4; ++q) {
            float4 a = p0[q]; w0[4*q]=a.x; w0[4*q+1]=a.y; w0[4*q+2]=a.z; w0[4*q+3]=a.w;
            float4 b = p1[q]; w1[4*q]=b.x; w1[4*q+1]=b.y; w1[4*q+2]=b.z; w1[4*q+3]=b.w;
            float4 c = p2[q]; w2[4*q]=c.x; w2[4*q+1]=c.y; w2[4*q+2]=c.z; w2[4*q+3]=c.w;
            float4 d = p3[q]; w3[4*q]=d.x; w3[4*q+1]=d.y; w3[4*q+2]=d.z; w3[4*q+3]=d.w;
        }
    }
    float wb[16];
    if (jt == 0) {
        const float4* pb = reinterpret_cast<const float4*>(W2R + 64 * 256 + o * 16);
        #pragma unroll
        for (int q = 0; q < 4; ++q) {
            float4 a = pb[q]; wb[4*q]=a.x; wb[4*q+1]=a.y; wb[4*q+2]=a.z; wb[4*q+3]=a.w;
        }
    }

    for (int n = bid; n < NN; n += 2048) {
        float xr[16];
        {
            const float4* p = reinterpret_cast<const float4*>(x) + (size_t)n * 4;
            float4 a = p[0], b = p[1], c = p[2], d = p[3];
            xr[0]=a.x; xr[1]=a.y; xr[2]=a.z;  xr[3]=a.w;
            xr[4]=b.x; xr[5]=b.y; xr[6]=b.z;  xr[7]=b.w;
            xr[8]=c.x; xr[9]=c.y; xr[10]=c.z; xr[11]=c.w;
            xr[12]=d.x; xr[13]=d.y; xr[14]=d.z; xr[15]=d.w;
        }
        ushort* tw = T + (size_t)n * TROW;

        float s0 = xr[0]*w0[0], s1 = xr[0]*w1[0], s2 = xr[0]*w2[0], s3 = xr[0]*w3[0];
        #pragma unroll
        for (int i = 1; i < 16; ++i) {
            s0 = fmaf(xr[i], w0[i], s0);
            s1 = fmaf(xr[i], w1[i], s1);
            s2 = fmaf(xr[i], w2[i], s2);
            s3 = fmaf(xr[i], w3[i], s3);
        }
        tw[tid]       = f2bf(s0);
        tw[tid + 256] = f2bf(s1);
        tw[tid + 512] = f2bf(s2);
        tw[tid + 768] = f2bf(s3);
        if (jt == 0) {
            float sb = xr[0]*wb[0];
            #pragma unroll
            for (int i = 1; i < 16; ++i) sb = fmaf(xr[i], wb[i], sb);
            tw[1024 + o] = f2bf(sb);
        }
    }
}

// edge_msg3 (r8/r10 proven shape, VGPR 56). ONLY change vs r10: h-phase reads
// W1T[j][0..16) -- contiguous 64B uniform row -> one s_load_dwordx16 per j
// (vs 16 stride-256B s_loads). Structure/regs otherwise identical.
__global__ __launch_bounds__(256) void edge_msg3(
    const int* __restrict__ eidx_s, const int* __restrict__ src,
    const int* __restrict__ dst, const float* __restrict__ ef,
    const float* __restrict__ W1T, const float* __restrict__ b1,
    const ushort* __restrict__ T, const int* __restrict__ offs_d,
    const int* __restrict__ pos_d, float* __restrict__ msgbuf)
{
    const int k0 = (blockIdx.x * blockDim.x + threadIdx.x) * 2;
    if (k0 >= NE) return;
    const bool two = (k0 + 1 < NE);
    const int k1 = two ? (k0 + 1) : k0;

    const int e0 = eidx_s[k0], e1 = eidx_s[k1];
    const int s0 = src[e0],    s1 = src[e1];

    float ea[16], eb[16];
    {
        const float4* p = reinterpret_cast<const float4*>(ef) + (size_t)e0 * 4;
        float4 a = p[0], b = p[1], c = p[2], d = p[3];
        ea[0]=a.x; ea[1]=a.y; ea[2]=a.z;  ea[3]=a.w;
        ea[4]=b.x; ea[5]=b.y; ea[6]=b.z;  ea[7]=b.w;
        ea[8]=c.x; ea[9]=c.y; ea[10]=c.z; ea[11]=c.w;
        ea[12]=d.x; ea[13]=d.y; ea[14]=d.z; ea[15]=d.w;
    }
    {
        const float4* p = reinterpret_cast<const float4*>(ef) + (size_t)e1 * 4;
        float4 a = p[0], b = p[1], c = p[2], d = p[3];
        eb[0]=a.x; eb[1]=a.y; eb[2]=a.z;  eb[3]=a.w;
        eb[4]=b.x; eb[5]=b.y; eb[6]=b.z;  eb[7]=b.w;
        eb[8]=c.x; eb[9]=c.y; eb[10]=c.z; eb[11]=c.w;
        eb[12]=d.x; eb[13]=d.y; eb[14]=d.z; eb[15]=d.w;
    }

    const ushort* tr0 = T + (size_t)s0 * TROW;
    const ushort* tr1 = T + (size_t)s1 * TROW;

    float m0[16], m1[16];
    {
        uint4 a = *reinterpret_cast<const uint4*>(tr0 + 1024);
        uint4 b = *reinterpret_cast<const uint4*>(tr0 + 1032);
        m0[0]=bflo(a.x);  m0[1]=bfhi(a.x);  m0[2]=bflo(a.y);  m0[3]=bfhi(a.y);
        m0[4]=bflo(a.z);  m0[5]=bfhi(a.z);  m0[6]=bflo(a.w);  m0[7]=bfhi(a.w);
        m0[8]=bflo(b.x);  m0[9]=bfhi(b.x);  m0[10]=bflo(b.y); m0[11]=bfhi(b.y);
        m0[12]=bflo(b.z); m0[13]=bfhi(b.z); m0[14]=bflo(b.w); m0[15]=bfhi(b.w);
    }
    {
        uint4 a = *reinterpret_cast<const uint4*>(tr1 + 1024);
        uint4 b = *reinterpret_cast<const uint4*>(tr1 + 1032);
        m1[0]=bflo(a.x);  m1[1]=bfhi(a.x);  m1[2]=bflo(a.y);  m1[3]=bfhi(a.y);
        m1[4]=bflo(a.z);  m1[5]=bfhi(a.z);  m1[6]=bflo(a.w);  m1[7]=bfhi(a.w);
        m1[8]=bflo(b.x);  m1[9]=bfhi(b.x);  m1[10]=bflo(b.y); m1[11]=bfhi(b.y);
        m1[12]=bflo(b.z); m1[13]=bfhi(b.z); m1[14]=bflo(b.w); m1[15]=bfhi(b.w);
    }

    for (int j = 0; j < HID; ++j) {
        const float* __restrict__ wr = W1T + j * 16;   // uniform, contiguous 64B
        float h0 = b1[j], h1 = h0;
        #pragma unroll
        for (int i = 0; i < 16; ++i) {
            const float w = wr[i];
            h0 = fmaf(ea[i], w, h0);
            h1 = fmaf(eb[i], w, h1);
        }
        h0 = fmaxf(h0, 0.f);
        h1 = fmaxf(h1, 0.f);

        uint4 a0 = *reinterpret_cast<const uint4*>(tr0 + j * 16);
        uint4 b0 = *reinterpret_cast<const uint4*>(tr0 + j * 16 + 8);
        uint4 a1 = *reinterpret_cast<const uint4*>(tr1 + j * 16);
        uint4 b1v = *reinterpret_cast<const uint4*>(tr1 + j * 16 + 8);
        m0[0]  = fmaf(h0, bflo(a0.x), m0[0]);  m0[1]  = fmaf(h0, bfhi(a0.x), m0[1]);
        m0[2]  = fmaf(h0, bflo(a0.y), m0[2]);  m0[3]  = fmaf(h0, bfhi(a0.y), m0[3]);
        m0[4]  = fmaf(h0, bflo(a0.z), m0[4]);  m0[5]  = fmaf(h0, bfhi(a0.z), m0[5]);
        m0[6]  = fmaf(h0, bflo(a0.w), m0[6]);  m0[7]  = fmaf(h0, bfhi(a0.w), m0[7]);
        m0[8]  = fmaf(h0, bflo(b0.x), m0[8]);  m0[9]  = fmaf(h0, bfhi(b0.x), m0[9]);
        m0[10] = fmaf(h0, bflo(b0.y), m0[10]); m0[11] = fmaf(h0, bfhi(b0.y), m0[11]);
        m0[12] = fmaf(h0, bflo(b0.z), m0[12]); m0[13] = fmaf(h0, bfhi(b0.z), m0[13]);
        m0[14] = fmaf(h0, bflo(b0.w), m0[14]); m0[15] = fmaf(h0, bfhi(b0.w), m0[15]);
        m1[0]  = fmaf(h1, bflo(a1.x), m1[0]);  m1[1]  = fmaf(h1, bfhi(a1.x), m1[1]);
        m1[2]  = fmaf(h1, bflo(a1.y), m1[2]);  m1[3]  = fmaf(h1, bfhi(a1.y), m1[3]);
        m1[4]  = fmaf(h1, bflo(a1.z), m1[4]);  m1[5]  = fmaf(h1, bfhi(a1.z), m1[5]);
        m1[6]  = fmaf(h1, bflo(a1.w), m1[6]);  m1[7]  = fmaf(h1, bfhi(a1.w), m1[7]);
        m1[8]  = fmaf(h1, bflo(b1v.x), m1[8]);  m1[9]  = fmaf(h1, bfhi(b1v.x), m1[9]);
        m1[10] = fmaf(h1, bflo(b1v.y), m1[10]); m1[11] = fmaf(h1, bfhi(b1v.y), m1[11]);
        m1[12] = fmaf(h1, bflo(b1v.z), m1[12]); m1[13] = fmaf(h1, bfhi(b1v.z), m1[13]);
        m1[14] = fmaf(h1, bflo(b1v.w), m1[14]); m1[15] = fmaf(h1, bfhi(b1v.w), m1[15]);
    }

    {
        const int d = dst[e0];
        const int slot = offs_d[d] + pos_d[e0];
        float4* mr = reinterpret_cast<float4*>(msgbuf + (size_t)slot * 16);
        mr[0] = make_float4(m0[0], m0[1], m0[2], m0[3]);
        mr[1] = make_float4(m0[4], m0[5], m0[6], m0[7]);
        mr[2] = make_float4(m0[8], m0[9], m0[10], m0[11]);
        mr[3] = make_float4(m0[12], m0[13], m0[14], m0[15]);
    }
    if (two) {
        const int d = dst[e1];
        const int slot = offs_d[d] + pos_d[e1];
        float4* mr = reinterpret_cast<float4*>(msgbuf + (size_t)slot * 16);
        mr[0] = make_float4(m1[0], m1[1], m1[2], m1[3]);
        mr[1] = make_float4(m1[4], m1[5], m1[6], m1[7]);
        mr[2] = make_float4(m1[8], m1[9], m1[10], m1[11]);
        mr[3] = make_float4(m1[12], m1[13], m1[14], m1[15]);
    }
}

// gather_mean3: thread = (node, o-quad); float4 reads/writes, 4 outputs/thread
// -> 4x fewer load instructions on this latency-bound kernel.
__global__ __launch_bounds__(256) void gather_mean3(
    const float* __restrict__ msgbuf, const int* __restrict__ offs_d,
    const float* __restrict__ x, const float* __restrict__ bias,
    float* __restrict__ out)
{
    const int t = blockIdx.x * blockDim.x + threadIdx.x;
    if (t >= NN * 4) return;
    const int n = t >> 2;
    const int oq = t & 3;
    const int beg = offs_d[n], end = offs_d[n + 1];
    float4 s = make_float4(0.f, 0.f, 0.f, 0.f);
    for (int k = beg; k < end; ++k) {
        const float4 v = *reinterpret_cast<const float4*>(msgbuf + (size_t)k * 16 + oq * 4);
        s.x += v.x; s.y += v.y; s.z += v.z; s.w += v.w;
    }
    const int d = end - beg;
    float4 r;
    if (d > 0) {
        const float inv = 1.f / (float)d;
        r = make_float4(s.x * inv, s.y * inv, s.z * inv, s.w * inv);
    } else {
        r = *reinterpret_cast<const float4*>(x + (size_t)n * 16 + oq * 4);
    }
    const float4 bv = *reinterpret_cast<const float4*>(bias + oq * 4);
    r.x += bv.x; r.y += bv.y; r.z += bv.z; r.w += bv.w;
    *reinterpret_cast<float4*>(out + (size_t)n * 16 + oq * 4) = r;
}

// ===========================================================================
// FALLBACK (round-2 proven path, ~36.4 MB ws)
// ===========================================================================
__global__ __launch_bounds__(1024) void dgc_scan(
    const int* __restrict__ deg, int* __restrict__ offs, int n)
{
    __shared__ int wsum[16];
    const int tid = threadIdx.x;
    const int lane = tid & 63;
    const int wid = tid >> 6;
    int carry = 0;
    for (int base = 0; base < n; base += 1024) {
        const int idx = base + tid;
        const int v = (idx < n) ? deg[idx] : 0;
        int s = v;
        #pragma unroll
        for (int d = 1; d < 64; d <<= 1) {
            int t = __shfl_up(s, d, 64);
            if (lane >= d) s += t;
        }
        if (lane == 63) wsum[wid] = s;
        __syncthreads();
        if (wid == 0 && lane < 16) {
            int w = wsum[lane];
            #pragma unroll
            for (int d = 1; d < 16; d <<= 1) {
                int t = __shfl_up(w, d, 64);
                if (lane >= d) w += t;
            }
            wsum[lane] = w;
        }
        __syncthreads();
        const int wpre = (wid == 0) ? 0 : wsum[wid - 1];
        if (idx < n) offs[idx] = carry + wpre + (s - v);
        carry += wsum[15];
        __syncthreads();
    }
    if (tid == 0) offs[n] = carry;
}

__global__ __launch_bounds__(256) void dgc_edge_csr(
    const float* __restrict__ x, const float* __restrict__ ef,
    const int* __restrict__ src, const int* __restrict__ dst,
    const float* __restrict__ W1, const float* __restrict__ b1,
    const float* __restrict__ W2, const float* __restrict__ b2,
    float* __restrict__ msg, int* __restrict__ pos, int* __restrict__ deg)
{
    const int e = blockIdx.x * blockDim.x + threadIdx.x;
    if (e >= NE) return;
    float efv[16];
    {
        const float4* p = reinterpret_cast<const float4*>(ef) + (size_t)e * 4;
        float4 a = p[0], b = p[1], c = p[2], d = p[3];
        efv[0]=a.x; efv[1]=a.y; efv[2]=a.z;  efv[3]=a.w;
        efv[4]=b.x; efv[5]=b.y; efv[6]=b.z;  efv[7]=b.w;
        efv[8]=c.x; efv[9]=c.y; efv[10]=c.z; efv[11]=c.w;
        efv[12]=d.x; efv[13]=d.y; efv[14]=d.z; efv[15]=d.w;
    }
    const int s = src[e];
    float xs[16];
    {
        const float4* p = reinterpret_cast<const float4*>(x) + (size_t)s * 4;
        float4 a = p[0], b = p[1], c = p[2], d = p[3];
        xs[0]=a.x; xs[1]=a.y; xs[2]=a.z;  xs[3]=a.w;
        xs[4]=b.x; xs[5]=b.y; xs[6]=b.z;  xs[7]=b.w;
        xs[8]=c.x; xs[9]=c.y; xs[10]=c.z; xs[11]=c.w;
        xs[12]=d.x; xs[13]=d.y; xs[14]=d.z; xs[15]=d.w;
    }
    float m[16];
    #pragma unroll
    for (int o = 0; o < 16; ++o) m[o] = 0.f;
    #pragma unroll
    for (int i = 0; i < 16; ++i) {
        const float xi = xs[i];
        #pragma unroll
        for (int o = 0; o < 16; ++o) m[o] = fmaf(xi, b2[i * 16 + o], m[o]);
    }
    for (int j = 0; j < HID; ++j) {
        float hj = b1[j];
        #pragma unroll
        for (int i = 0; i < 16; ++i) hj = fmaf(efv[i], W1[i * HID + j], hj);
        hj = fmaxf(hj, 0.f);
        const float* __restrict__ w2r = W2 + (size_t)j * 256;
        float t[16];
        #pragma unroll
        for (int o = 0; o < 16; ++o) t[o] = 0.f;
        #pragma unroll
        for (int i = 0; i < 16; ++i) {
            const float xi = xs[i];
            #pragma unroll
            for (int o = 0; o < 16; ++o) t[o] = fmaf(xi, w2r[i * 16 + o], t[o]);
        }
        #pragma unroll
        for (int o = 0; o < 16; ++o) m[o] = fmaf(hj, t[o], m[o]);
    }
    float4* mr = reinterpret_cast<float4*>(msg + (size_t)e * 16);
    mr[0] = make_float4(m[0], m[1], m[2], m[3]);
    mr[1] = make_float4(m[4], m[5], m[6], m[7]);
    mr[2] = make_float4(m[8], m[9], m[10], m[11]);
    mr[3] = make_float4(m[12], m[13], m[14], m[15]);
    pos[e] = atomicAdd(deg + dst[e], 1);
}

__global__ __launch_bounds__(256) void dgc_scatter(
    const int* __restrict__ dst, const int* __restrict__ pos,
    const int* __restrict__ offs, int* __restrict__ eidx)
{
    const int e = blockIdx.x * blockDim.x + threadIdx.x;
    if (e >= NE) return;
    eidx[offs[dst[e]] + pos[e]] = e;
}

__global__ __launch_bounds__(256) void dgc_gather(
    const float* __restrict__ msg, const int* __restrict__ offs,
    const int* __restrict__ eidx, const float* __restrict__ x,
    const float* __restrict__ bias, float* __restrict__ out)
{
    const int t = blockIdx.x * blockDim.x + threadIdx.x;
    if (t >= NN * FOUT) return;
    const int n = t >> 4;
    const int o = t & 15;
    const int beg = offs[n], end = offs[n + 1];
    float s = 0.f;
    for (int k = beg; k < end; ++k)
        s += msg[(size_t)eidx[k] * 16 + o];
    const int d = end - beg;
    const float v = (d > 0) ? (s / (float)d) : x[t];
    out[t] = v + bias[o];
}

extern "C" void kernel_launch(void* const* d_in, const int* in_sizes, int n_in,
                              void* d_out, int out_size, void* d_ws, size_t ws_size,
                              hipStream_t stream) {
    const float* x    = (const float*)d_in[0];
    const float* ef   = (const float*)d_in[1];
    const int*   src  = (const int*)d_in[2];
    const int*   dst  = (const int*)d_in[3];
    const float* W1   = (const float*)d_in[4];
    const float* b1   = (const float*)d_in[5];
    const float* W2   = (const float*)d_in[6];
    const float* b2   = (const float*)d_in[7];
    const float* bias = (const float*)d_in[8];
    float* out = (float*)d_out;

    // main-path ws layout
    ushort* T      = (ushort*)d_ws;                       // NN*TROW bf16 (104 MB)
    float*  msgbuf = (float*)(T + (size_t)NN * TROW);     // NE*16 f32   (32 MB)
    float*  W2R    = msgbuf + (size_t)NE * 16;            // 65*256
    float*  W1T    = W2R + 65 * 256;                      // 64*16
    int*    deg_s  = (int*)(W1T + 64 * 16);               // NN
    int*    deg_d  = deg_s + NN;                          // NN
    int*    offs_s = deg_d + NN;                          // NN+1
    int*    offs_d = offs_s + NN + 1;                     // NN+1
    int*    pos_s  = offs_d + NN + 1;                     // NE
    int*    pos_d  = pos_s + NE;                          // NE
    int*    eidx_s = pos_d + NE;                          // NE
    const size_t needed =
        (size_t)NN * TROW * 2 +
        ((size_t)NE * 16 + 65 * 256 + 64 * 16) * 4 +
        ((size_t)2 * NN + 2 * (NN + 1) + (size_t)3 * NE) * 4;

    const int nbc = (NE + 255) / 256;   // 1954

    if (ws_size >= needed) {
        hipMemsetAsync(deg_s, 0, (size_t)2 * NN * sizeof(int), stream);
        count_w2r<<<nbc + 65, 256, 0, stream>>>(
            src, dst, deg_s, pos_s, deg_d, pos_d, W2, b2, W1, W2R, W1T);
        dgc_scan2<<<2, 1024, 0, stream>>>(deg_s, offs_s, deg_d, offs_d);
        scatter_tprep<<<nbc + 2048, 256, 0, stream>>>(
            src, pos_s, offs_s, eidx_s, x, W2R, T);
        edge_msg3<<<(NE / 2 + 255) / 256, 256, 0, stream>>>(
            eidx_s, src, dst, ef, W1T, b1, T, offs_d, pos_d, msgbuf);
        gather_mean3<<<(NN * 4 + 255) / 256, 256, 0, stream>>>(
            msgbuf, offs_d, x, bias, out);
    } else {
        // round-2 fallback
        float* msg  = (float*)d_ws;
        int*   deg  = (int*)(msg + (size_t)NE * 16);
        int*   offs = deg + NN;
        int*   pos  = offs + NN + 1;
        int*   eidx = pos + NE;
        hipMemsetAsync(deg, 0, (size_t)NN * sizeof(int), stream);
        dgc_edge_csr<<<(NE + 255) / 256, 256, 0, stream>>>(
            x, ef, src, dst, W1, b1, W2, b2, msg, pos, deg);
        dgc_scan<<<1, 1024, 0, stream>>>(deg, offs, NN);
        dgc_scatter<<<(NE + 255) / 256, 256, 0, stream>>>(dst, pos, offs, eidx);
        dgc_gather<<<(NN * FOUT + 255) / 256, 256, 0, stream>>>(
            msg, offs, eidx, x, bias, out);
    }
}

// Round 13
// 213.696 us; speedup vs baseline: 1.2314x; 1.0133x over previous
//
#include <hip/hip_runtime.h>

#define NN 50000
#define NE 500000
#define FIN 16
#define FOUT 16
#define HID 64
#define TROW 1040   // ushorts/node: [jp<32][o<16][2] f16 pairs (j=2jp,2jp+1) + b2 row f16 @1024

typedef unsigned int  uint;
typedef unsigned short ushort;
typedef __fp16 h2 __attribute__((ext_vector_type(2)));   // matches cvt_pkrtz/fdot2 builtin type

__device__ __forceinline__ ushort f2h(float f) {            // f32 -> f16 bits
    union { __fp16 h; ushort s; } v; v.h = (__fp16)f; return v.s;
}
__device__ __forceinline__ h2 u2h2(uint u) {                // uint -> 2xf16
    union { uint u; h2 h; } v; v.u = u; return v.h;
}
__device__ __forceinline__ float h2lo(uint u) {
    union { ushort s; __fp16 h; } v; v.s = (ushort)(u & 0xffffu); return (float)v.h;
}
__device__ __forceinline__ float h2hi(uint u) {
    union { ushort s; __fp16 h; } v; v.s = (ushort)(u >> 16); return (float)v.h;
}

// ===========================================================================
// MAIN PATH. Round-11 lesson: edge kernel 75us invariant; VALU time ~34us of
// which ~1/3 is bf16 unpack. Round-12/13: T stored as f16 j-pairs; m-update
// via v_dot2_f32_f16 (fdot2) -> unpack eliminated, ~47% fewer VALU ops, same
// loads/VGPR. f16 also improves accuracy vs bf16 (11-bit vs 8-bit mantissa).
// (r12 was a compile-only failure: h2 must be __fp16-based, not _Float16.)
// ===========================================================================

// blocks [0,1954): count ranks+degrees. blocks [1954,+65): W2R/W1T transforms.
__global__ __launch_bounds__(256) void count_w2r(
    const int* __restrict__ src, const int* __restrict__ dst,
    int* __restrict__ deg_s, int* __restrict__ pos_s,
    int* __restrict__ deg_d, int* __restrict__ pos_d,
    const float* __restrict__ W2, const float* __restrict__ b2,
    const float* __restrict__ W1, float* __restrict__ W2R,
    float* __restrict__ W1T)
{
    const int nbc = (NE + 255) / 256;
    if ((int)blockIdx.x < nbc) {
        const int e = blockIdx.x * 256 + threadIdx.x;
        if (e < NE) {
            pos_s[e] = atomicAdd(deg_s + src[e], 1);
            pos_d[e] = atomicAdd(deg_d + dst[e], 1);
        }
    } else {
        const int t = (blockIdx.x - nbc) * 256 + threadIdx.x;
        if (t < 64 * 16) {
            const int j = t >> 4, i = t & 15;
            W1T[t] = W1[i * HID + j];          // W1T[j][i] = W1[i][j]
        }
        if (t < 65 * 256) {
            const int j = t >> 8;
            const int col = t & 255;           // col = i*16 + o
            const int i = col >> 4, o = col & 15;
            const float v = (j < 64) ? W2[j * 256 + col] : b2[col];
            W2R[j * 256 + o * 16 + i] = v;     // W2R[j][o][i]
        }
    }
}

// two independent exclusive scans (block 0: A, block 1: B), n=NN each
__global__ __launch_bounds__(1024) void dgc_scan2(
    const int* __restrict__ degA, int* __restrict__ offA,
    const int* __restrict__ degB, int* __restrict__ offB)
{
    const int* __restrict__ deg = blockIdx.x ? degB : degA;
    int* __restrict__ offs      = blockIdx.x ? offB : offA;
    __shared__ int wsum[16];
    const int tid = threadIdx.x;
    const int lane = tid & 63;
    const int wid = tid >> 6;
    int carry = 0;
    for (int base = 0; base < NN; base += 1024) {
        const int idx = base + tid;
        const int v = (idx < NN) ? deg[idx] : 0;
        int s = v;
        #pragma unroll
        for (int d = 1; d < 64; d <<= 1) {
            int t = __shfl_up(s, d, 64);
            if (lane >= d) s += t;
        }
        if (lane == 63) wsum[wid] = s;
        __syncthreads();
        if (wid == 0 && lane < 16) {
            int w = wsum[lane];
            #pragma unroll
            for (int d = 1; d < 16; d <<= 1) {
                int t = __shfl_up(w, d, 64);
                if (lane >= d) w += t;
            }
            wsum[lane] = w;
        }
        __syncthreads();
        const int wpre = (wid == 0) ? 0 : wsum[wid - 1];
        if (idx < NN) offs[idx] = carry + wpre + (s - v);
        carry += wsum[15];
        __syncthreads();
    }
    if (tid == 0) offs[NN] = carry;
}

// blocks [0,1954): scatter edge ids into src-CSR. blocks [1954,+2048): tprep
// (thread (jt,o) owns 4 W2R rows in regs; j-pair-interleaved f16 stores).
__global__ __launch_bounds__(256) void scatter_tprep(
    const int* __restrict__ src, const int* __restrict__ pos_s,
    const int* __restrict__ offs_s, int* __restrict__ eidx_s,
    const float* __restrict__ x, const float* __restrict__ W2R,
    ushort* __restrict__ T)
{
    const int nbs = (NE + 255) / 256;
    if ((int)blockIdx.x < nbs) {
        const int e = blockIdx.x * 256 + threadIdx.x;
        if (e < NE) eidx_s[offs_s[src[e]] + pos_s[e]] = e;
        return;
    }
    const int bid = blockIdx.x - nbs;      // 0..2047
    const int tid = threadIdx.x;
    const int jt = tid >> 4, o = tid & 15;
    // element (j,o) lives at ushort offset (j>>1)*32 + o*2 + (j&1); for
    // j = jt+16k that is off0 + 256k with off0 below (same coalescing as r11).
    const int off0 = (jt >> 1) * 32 + o * 2 + (jt & 1);

    float w0[16], w1[16], w2[16], w3[16];
    {
        const float4* p0 = reinterpret_cast<const float4*>(W2R + (jt     ) * 256 + o * 16);
        const float4* p1 = reinterpret_cast<const float4*>(W2R + (jt + 16) * 256 + o * 16);
        const float4* p2 = reinterpret_cast<const float4*>(W2R + (jt + 32) * 256 + o * 16);
        const float4* p3 = reinterpret_cast<const float4*>(W2R + (jt + 48) * 256 + o * 16);
        #pragma unroll
        for (int q = 0; q < 4; ++q) {
            float4 a = p0[q]; w0[4*q]=a.x; w0[4*q+1]=a.y; w0[4*q+2]=a.z; w0[4*q+3]=a.w;
            float4 b = p1[q]; w1[4*q]=b.x; w1[4*q+1]=b.y; w1[4*q+2]=b.z; w1[4*q+3]=b.w;
            float4 c = p2[q]; w2[4*q]=c.x; w2[4*q+1]=c.y; w2[4*q+2]=c.z; w2[4*q+3]=c.w;
            float4 d = p3[q]; w3[4*q]=d.x; w3[4*q+1]=d.y; w3[4*q+2]=d.z; w3[4*q+3]=d.w;
        }
    }
    float wb[16];
    if (jt == 0) {
        const float4* pb = reinterpret_cast<const float4*>(W2R + 64 * 256 + o * 16);
        #pragma unroll
        for (int q = 0; q < 4; ++q) {
            float4 a = pb[q]; wb[4*q]=a.x; wb[4*q+1]=a.y; wb[4*q+2]=a.z; wb[4*q+3]=a.w;
        }
    }

    for (int n = bid; n < NN; n += 2048) {
        float xr[16];
        {
            const float4* p = reinterpret_cast<const float4*>(x) + (size_t)n * 4;
            float4 a = p[0], b = p[1], c = p[2], d = p[3];
            xr[0]=a.x; xr[1]=a.y; xr[2]=a.z;  xr[3]=a.w;
            xr[4]=b.x; xr[5]=b.y; xr[6]=b.z;  xr[7]=b.w;
            xr[8]=c.x; xr[9]=c.y; xr[10]=c.z; xr[11]=c.w;
            xr[12]=d.x; xr[13]=d.y; xr[14]=d.z; xr[15]=d.w;
        }
        ushort* tw = T + (size_t)n * TROW;

        float s0 = xr[0]*w0[0], s1 = xr[0]*w1[0], s2 = xr[0]*w2[0], s3 = xr[0]*w3[0];
        #pragma unroll
        for (int i = 1; i < 16; ++i) {
            s0 = fmaf(xr[i], w0[i], s0);
            s1 = fmaf(xr[i], w1[i], s1);
            s2 = fmaf(xr[i], w2[i], s2);
            s3 = fmaf(xr[i], w3[i], s3);
        }
        tw[off0]       = f2h(s0);
        tw[off0 + 256] = f2h(s1);
        tw[off0 + 512] = f2h(s2);
        tw[off0 + 768] = f2h(s3);
        if (jt == 0) {
            float sb = xr[0]*wb[0];
            #pragma unroll
            for (int i = 1; i < 16; ++i) sb = fmaf(xr[i], wb[i], sb);
            tw[1024 + o] = f2h(sb);
        }
    }
}

// edge_msg5: r8/r10 proven 2-slot structure; m-update via v_dot2_f32_f16 on
// j-paired f16 T rows (no unpack ops). No atomics; direct dst-slot write.
__global__ __launch_bounds__(256) void edge_msg5(
    const int* __restrict__ eidx_s, const int* __restrict__ src,
    const int* __restrict__ dst, const float* __restrict__ ef,
    const float* __restrict__ W1T, const float* __restrict__ b1,
    const ushort* __restrict__ T, const int* __restrict__ offs_d,
    const int* __restrict__ pos_d, float* __restrict__ msgbuf)
{
    const int k0 = (blockIdx.x * blockDim.x + threadIdx.x) * 2;
    if (k0 >= NE) return;
    const bool two = (k0 + 1 < NE);
    const int k1 = two ? (k0 + 1) : k0;

    const int e0 = eidx_s[k0], e1 = eidx_s[k1];
    const int s0 = src[e0],    s1 = src[e1];

    float ea[16], eb[16];
    {
        const float4* p = reinterpret_cast<const float4*>(ef) + (size_t)e0 * 4;
        float4 a = p[0], b = p[1], c = p[2], d = p[3];
        ea[0]=a.x; ea[1]=a.y; ea[2]=a.z;  ea[3]=a.w;
        ea[4]=b.x; ea[5]=b.y; ea[6]=b.z;  ea[7]=b.w;
        ea[8]=c.x; ea[9]=c.y; ea[10]=c.z; ea[11]=c.w;
        ea[12]=d.x; ea[13]=d.y; ea[14]=d.z; ea[15]=d.w;
    }
    {
        const float4* p = reinterpret_cast<const float4*>(ef) + (size_t)e1 * 4;
        float4 a = p[0], b = p[1], c = p[2], d = p[3];
        eb[0]=a.x; eb[1]=a.y; eb[2]=a.z;  eb[3]=a.w;
        eb[4]=b.x; eb[5]=b.y; eb[6]=b.z;  eb[7]=b.w;
        eb[8]=c.x; eb[9]=c.y; eb[10]=c.z; eb[11]=c.w;
        eb[12]=d.x; eb[13]=d.y; eb[14]=d.z; eb[15]=d.w;
    }

    const ushort* tr0 = T + (size_t)s0 * TROW;
    const ushort* tr1 = T + (size_t)s1 * TROW;

    float m0[16], m1[16];
    {   // b2 row (f16 @ offset 1024): one-time unpack
        uint4 a = *reinterpret_cast<const uint4*>(tr0 + 1024);
        uint4 b = *reinterpret_cast<const uint4*>(tr0 + 1032);
        m0[0]=h2lo(a.x);  m0[1]=h2hi(a.x);  m0[2]=h2lo(a.y);  m0[3]=h2hi(a.y);
        m0[4]=h2lo(a.z);  m0[5]=h2hi(a.z);  m0[6]=h2lo(a.w);  m0[7]=h2hi(a.w);
        m0[8]=h2lo(b.x);  m0[9]=h2hi(b.x);  m0[10]=h2lo(b.y); m0[11]=h2hi(b.y);
        m0[12]=h2lo(b.z); m0[13]=h2hi(b.z); m0[14]=h2lo(b.w); m0[15]=h2hi(b.w);
    }
    {
        uint4 a = *reinterpret_cast<const uint4*>(tr1 + 1024);
        uint4 b = *reinterpret_cast<const uint4*>(tr1 + 1032);
        m1[0]=h2lo(a.x);  m1[1]=h2hi(a.x);  m1[2]=h2lo(a.y);  m1[3]=h2hi(a.y);
        m1[4]=h2lo(a.z);  m1[5]=h2hi(a.z);  m1[6]=h2lo(a.w);  m1[7]=h2hi(a.w);
        m1[8]=h2lo(b.x);  m1[9]=h2hi(b.x);  m1[10]=h2lo(b.y); m1[11]=h2hi(b.y);
        m1[12]=h2lo(b.z); m1[13]=h2hi(b.z); m1[14]=h2lo(b.w); m1[15]=h2hi(b.w);
    }

    for (int jp = 0; jp < 32; ++jp) {
        const float* __restrict__ wr = W1T + jp * 32;   // rows j0=2jp, j1=2jp+1
        const float ba = b1[2 * jp], bb = b1[2 * jp + 1];
        float h0a = ba, h0b = bb, h1a = ba, h1b = bb;
        #pragma unroll
        for (int i = 0; i < 16; ++i) {
            const float wa = wr[i], wb = wr[16 + i];
            h0a = fmaf(ea[i], wa, h0a);
            h0b = fmaf(ea[i], wb, h0b);
            h1a = fmaf(eb[i], wa, h1a);
            h1b = fmaf(eb[i], wb, h1b);
        }
        h0a = fmaxf(h0a, 0.f); h0b = fmaxf(h0b, 0.f);
        h1a = fmaxf(h1a, 0.f); h1b = fmaxf(h1b, 0.f);
        const h2 hp0 = __builtin_amdgcn_cvt_pkrtz(h0a, h0b);
        const h2 hp1 = __builtin_amdgcn_cvt_pkrtz(h1a, h1b);

        const uint4 a0 = *reinterpret_cast<const uint4*>(tr0 + jp * 32);
        const uint4 b0 = *reinterpret_cast<const uint4*>(tr0 + jp * 32 + 8);
        const uint4 c0 = *reinterpret_cast<const uint4*>(tr0 + jp * 32 + 16);
        const uint4 d0 = *reinterpret_cast<const uint4*>(tr0 + jp * 32 + 24);
        const uint4 a1 = *reinterpret_cast<const uint4*>(tr1 + jp * 32);
        const uint4 b1u = *reinterpret_cast<const uint4*>(tr1 + jp * 32 + 8);
        const uint4 c1 = *reinterpret_cast<const uint4*>(tr1 + jp * 32 + 16);
        const uint4 d1 = *reinterpret_cast<const uint4*>(tr1 + jp * 32 + 24);

        m0[0]  = __builtin_amdgcn_fdot2(hp0, u2h2(a0.x), m0[0],  false);
        m0[1]  = __builtin_amdgcn_fdot2(hp0, u2h2(a0.y), m0[1],  false);
        m0[2]  = __builtin_amdgcn_fdot2(hp0, u2h2(a0.z), m0[2],  false);
        m0[3]  = __builtin_amdgcn_fdot2(hp0, u2h2(a0.w), m0[3],  false);
        m0[4]  = __builtin_amdgcn_fdot2(hp0, u2h2(b0.x), m0[4],  false);
        m0[5]  = __builtin_amdgcn_fdot2(hp0, u2h2(b0.y), m0[5],  false);
        m0[6]  = __builtin_amdgcn_fdot2(hp0, u2h2(b0.z), m0[6],  false);
        m0[7]  = __builtin_amdgcn_fdot2(hp0, u2h2(b0.w), m0[7],  false);
        m0[8]  = __builtin_amdgcn_fdot2(hp0, u2h2(c0.x), m0[8],  false);
        m0[9]  = __builtin_amdgcn_fdot2(hp0, u2h2(c0.y), m0[9],  false);
        m0[10] = __builtin_amdgcn_fdot2(hp0, u2h2(c0.z), m0[10], false);
        m0[11] = __builtin_amdgcn_fdot2(hp0, u2h2(c0.w), m0[11], false);
        m0[12] = __builtin_amdgcn_fdot2(hp0, u2h2(d0.x), m0[12], false);
        m0[13] = __builtin_amdgcn_fdot2(hp0, u2h2(d0.y), m0[13], false);
        m0[14] = __builtin_amdgcn_fdot2(hp0, u2h2(d0.z), m0[14], false);
        m0[15] = __builtin_amdgcn_fdot2(hp0, u2h2(d0.w), m0[15], false);

        m1[0]  = __builtin_amdgcn_fdot2(hp1, u2h2(a1.x), m1[0],  false);
        m1[1]  = __builtin_amdgcn_fdot2(hp1, u2h2(a1.y), m1[1],  false);
        m1[2]  = __builtin_amdgcn_fdot2(hp1, u2h2(a1.z), m1[2],  false);
        m1[3]  = __builtin_amdgcn_fdot2(hp1, u2h2(a1.w), m1[3],  false);
        m1[4]  = __builtin_amdgcn_fdot2(hp1, u2h2(b1u.x), m1[4],  false);
        m1[5]  = __builtin_amdgcn_fdot2(hp1, u2h2(b1u.y), m1[5],  false);
        m1[6]  = __builtin_amdgcn_fdot2(hp1, u2h2(b1u.z), m1[6],  false);
        m1[7]  = __builtin_amdgcn_fdot2(hp1, u2h2(b1u.w), m1[7],  false);
        m1[8]  = __builtin_amdgcn_fdot2(hp1, u2h2(c1.x), m1[8],  false);
        m1[9]  = __builtin_amdgcn_fdot2(hp1, u2h2(c1.y), m1[9],  false);
        m1[10] = __builtin_amdgcn_fdot2(hp1, u2h2(c1.z), m1[10], false);
        m1[11] = __builtin_amdgcn_fdot2(hp1, u2h2(c1.w), m1[11], false);
        m1[12] = __builtin_amdgcn_fdot2(hp1, u2h2(d1.x), m1[12], false);
        m1[13] = __builtin_amdgcn_fdot2(hp1, u2h2(d1.y), m1[13], false);
        m1[14] = __builtin_amdgcn_fdot2(hp1, u2h2(d1.z), m1[14], false);
        m1[15] = __builtin_amdgcn_fdot2(hp1, u2h2(d1.w), m1[15], false);
    }

    {
        const int d = dst[e0];
        const int slot = offs_d[d] + pos_d[e0];
        float4* mr = reinterpret_cast<float4*>(msgbuf + (size_t)slot * 16);
        mr[0] = make_float4(m0[0], m0[1], m0[2], m0[3]);
        mr[1] = make_float4(m0[4], m0[5], m0[6], m0[7]);
        mr[2] = make_float4(m0[8], m0[9], m0[10], m0[11]);
        mr[3] = make_float4(m0[12], m0[13], m0[14], m0[15]);
    }
    if (two) {
        const int d = dst[e1];
        const int slot = offs_d[d] + pos_d[e1];
        float4* mr = reinterpret_cast<float4*>(msgbuf + (size_t)slot * 16);
        mr[0] = make_float4(m1[0], m1[1], m1[2], m1[3]);
        mr[1] = make_float4(m1[4], m1[5], m1[6], m1[7]);
        mr[2] = make_float4(m1[8], m1[9], m1[10], m1[11]);
        mr[3] = make_float4(m1[12], m1[13], m1[14], m1[15]);
    }
}

// gather_mean3: thread = (node, o-quad); float4 reads/writes, 4 outputs/thread
__global__ __launch_bounds__(256) void gather_mean3(
    const float* __restrict__ msgbuf, const int* __restrict__ offs_d,
    const float* __restrict__ x, const float* __restrict__ bias,
    float* __restrict__ out)
{
    const int t = blockIdx.x * blockDim.x + threadIdx.x;
    if (t >= NN * 4) return;
    const int n = t >> 2;
    const int oq = t & 3;
    const int beg = offs_d[n], end = offs_d[n + 1];
    float4 s = make_float4(0.f, 0.f, 0.f, 0.f);
    for (int k = beg; k < end; ++k) {
        const float4 v = *reinterpret_cast<const float4*>(msgbuf + (size_t)k * 16 + oq * 4);
        s.x += v.x; s.y += v.y; s.z += v.z; s.w += v.w;
    }
    const int d = end - beg;
    float4 r;
    if (d > 0) {
        const float inv = 1.f / (float)d;
        r = make_float4(s.x * inv, s.y * inv, s.z * inv, s.w * inv);
    } else {
        r = *reinterpret_cast<const float4*>(x + (size_t)n * 16 + oq * 4);
    }
    const float4 bv = *reinterpret_cast<const float4*>(bias + oq * 4);
    r.x += bv.x; r.y += bv.y; r.z += bv.z; r.w += bv.w;
    *reinterpret_cast<float4*>(out + (size_t)n * 16 + oq * 4) = r;
}

// ===========================================================================
// FALLBACK (round-2 proven path, ~36.4 MB ws)
// ===========================================================================
__global__ __launch_bounds__(1024) void dgc_scan(
    const int* __restrict__ deg, int* __restrict__ offs, int n)
{
    __shared__ int wsum[16];
    const int tid = threadIdx.x;
    const int lane = tid & 63;
    const int wid = tid >> 6;
    int carry = 0;
    for (int base = 0; base < n; base += 1024) {
        const int idx = base + tid;
        const int v = (idx < n) ? deg[idx] : 0;
        int s = v;
        #pragma unroll
        for (int d = 1; d < 64; d <<= 1) {
            int t = __shfl_up(s, d, 64);
            if (lane >= d) s += t;
        }
        if (lane == 63) wsum[wid] = s;
        __syncthreads();
        if (wid == 0 && lane < 16) {
            int w = wsum[lane];
            #pragma unroll
            for (int d = 1; d < 16; d <<= 1) {
                int t = __shfl_up(w, d, 64);
                if (lane >= d) w += t;
            }
            wsum[lane] = w;
        }
        __syncthreads();
        const int wpre = (wid == 0) ? 0 : wsum[wid - 1];
        if (idx < n) offs[idx] = carry + wpre + (s - v);
        carry += wsum[15];
        __syncthreads();
    }
    if (tid == 0) offs[n] = carry;
}

__global__ __launch_bounds__(256) void dgc_edge_csr(
    const float* __restrict__ x, const float* __restrict__ ef,
    const int* __restrict__ src, const int* __restrict__ dst,
    const float* __restrict__ W1, const float* __restrict__ b1,
    const float* __restrict__ W2, const float* __restrict__ b2,
    float* __restrict__ msg, int* __restrict__ pos, int* __restrict__ deg)
{
    const int e = blockIdx.x * blockDim.x + threadIdx.x;
    if (e >= NE) return;
    float efv[16];
    {
        const float4* p = reinterpret_cast<const float4*>(ef) + (size_t)e * 4;
        float4 a = p[0], b = p[1], c = p[2], d = p[3];
        efv[0]=a.x; efv[1]=a.y; efv[2]=a.z;  efv[3]=a.w;
        efv[4]=b.x; efv[5]=b.y; efv[6]=b.z;  efv[7]=b.w;
        efv[8]=c.x; efv[9]=c.y; efv[10]=c.z; efv[11]=c.w;
        efv[12]=d.x; efv[13]=d.y; efv[14]=d.z; efv[15]=d.w;
    }
    const int s = src[e];
    float xs[16];
    {
        const float4* p = reinterpret_cast<const float4*>(x) + (size_t)s * 4;
        float4 a = p[0], b = p[1], c = p[2], d = p[3];
        xs[0]=a.x; xs[1]=a.y; xs[2]=a.z;  xs[3]=a.w;
        xs[4]=b.x; xs[5]=b.y; xs[6]=b.z;  xs[7]=b.w;
        xs[8]=c.x; xs[9]=c.y; xs[10]=c.z; xs[11]=c.w;
        xs[12]=d.x; xs[13]=d.y; xs[14]=d.z; xs[15]=d.w;
    }
    float m[16];
    #pragma unroll
    for (int o = 0; o < 16; ++o) m[o] = 0.f;
    #pragma unroll
    for (int i = 0; i < 16; ++i) {
        const float xi = xs[i];
        #pragma unroll
        for (int o = 0; o < 16; ++o) m[o] = fmaf(xi, b2[i * 16 + o], m[o]);
    }
    for (int j = 0; j < HID; ++j) {
        float hj = b1[j];
        #pragma unroll
        for (int i = 0; i < 16; ++i) hj = fmaf(efv[i], W1[i * HID + j], hj);
        hj = fmaxf(hj, 0.f);
        const float* __restrict__ w2r = W2 + (size_t)j * 256;
        float t[16];
        #pragma unroll
        for (int o = 0; o < 16; ++o) t[o] = 0.f;
        #pragma unroll
        for (int i = 0; i < 16; ++i) {
            const float xi = xs[i];
            #pragma unroll
            for (int o = 0; o < 16; ++o) t[o] = fmaf(xi, w2r[i * 16 + o], t[o]);
        }
        #pragma unroll
        for (int o = 0; o < 16; ++o) m[o] = fmaf(hj, t[o], m[o]);
    }
    float4* mr = reinterpret_cast<float4*>(msg + (size_t)e * 16);
    mr[0] = make_float4(m[0], m[1], m[2], m[3]);
    mr[1] = make_float4(m[4], m[5], m[6], m[7]);
    mr[2] = make_float4(m[8], m[9], m[10], m[11]);
    mr[3] = make_float4(m[12], m[13], m[14], m[15]);
    pos[e] = atomicAdd(deg + dst[e], 1);
}

__global__ __launch_bounds__(256) void dgc_scatter(
    const int* __restrict__ dst, const int* __restrict__ pos,
    const int* __restrict__ offs, int* __restrict__ eidx)
{
    const int e = blockIdx.x * blockDim.x + threadIdx.x;
    if (e >= NE) return;
    eidx[offs[dst[e]] + pos[e]] = e;
}

__global__ __launch_bounds__(256) void dgc_gather(
    const float* __restrict__ msg, const int* __restrict__ offs,
    const int* __restrict__ eidx, const float* __restrict__ x,
    const float* __restrict__ bias, float* __restrict__ out)
{
    const int t = blockIdx.x * blockDim.x + threadIdx.x;
    if (t >= NN * FOUT) return;
    const int n = t >> 4;
    const int o = t & 15;
    const int beg = offs[n], end = offs[n + 1];
    float s = 0.f;
    for (int k = beg; k < end; ++k)
        s += msg[(size_t)eidx[k] * 16 + o];
    const int d = end - beg;
    const float v = (d > 0) ? (s / (float)d) : x[t];
    out[t] = v + bias[o];
}

extern "C" void kernel_launch(void* const* d_in, const int* in_sizes, int n_in,
                              void* d_out, int out_size, void* d_ws, size_t ws_size,
                              hipStream_t stream) {
    const float* x    = (const float*)d_in[0];
    const float* ef   = (const float*)d_in[1];
    const int*   src  = (const int*)d_in[2];
    const int*   dst  = (const int*)d_in[3];
    const float* W1   = (const float*)d_in[4];
    const float* b1   = (const float*)d_in[5];
    const float* W2   = (const float*)d_in[6];
    const float* b2   = (const float*)d_in[7];
    const float* bias = (const float*)d_in[8];
    float* out = (float*)d_out;

    // main-path ws layout
    ushort* T      = (ushort*)d_ws;                       // NN*TROW f16 (104 MB)
    float*  msgbuf = (float*)(T + (size_t)NN * TROW);     // NE*16 f32   (32 MB)
    float*  W2R    = msgbuf + (size_t)NE * 16;            // 65*256
    float*  W1T    = W2R + 65 * 256;                      // 64*16
    int*    deg_s  = (int*)(W1T + 64 * 16);               // NN
    int*    deg_d  = deg_s + NN;                          // NN
    int*    offs_s = deg_d + NN;                          // NN+1
    int*    offs_d = offs_s + NN + 1;                     // NN+1
    int*    pos_s  = offs_d + NN + 1;                     // NE
    int*    pos_d  = pos_s + NE;                          // NE
    int*    eidx_s = pos_d + NE;                          // NE
    const size_t needed =
        (size_t)NN * TROW * 2 +
        ((size_t)NE * 16 + 65 * 256 + 64 * 16) * 4 +
        ((size_t)2 * NN + 2 * (NN + 1) + (size_t)3 * NE) * 4;

    const int nbc = (NE + 255) / 256;   // 1954

    if (ws_size >= needed) {
        hipMemsetAsync(deg_s, 0, (size_t)2 * NN * sizeof(int), stream);
        count_w2r<<<nbc + 65, 256, 0, stream>>>(
            src, dst, deg_s, pos_s, deg_d, pos_d, W2, b2, W1, W2R, W1T);
        dgc_scan2<<<2, 1024, 0, stream>>>(deg_s, offs_s, deg_d, offs_d);
        scatter_tprep<<<nbc + 2048, 256, 0, stream>>>(
            src, pos_s, offs_s, eidx_s, x, W2R, T);
        edge_msg5<<<(NE / 2 + 255) / 256, 256, 0, stream>>>(
            eidx_s, src, dst, ef, W1T, b1, T, offs_d, pos_d, msgbuf);
        gather_mean3<<<(NN * 4 + 255) / 256, 256, 0, stream>>>(
            msgbuf, offs_d, x, bias, out);
    } else {
        // round-2 fallback
        float* msg  = (float*)d_ws;
        int*   deg  = (int*)(msg + (size_t)NE * 16);
        int*   offs = deg + NN;
        int*   pos  = offs + NN + 1;
        int*   eidx = pos + NE;
        hipMemsetAsync(deg, 0, (size_t)NN * sizeof(int), stream);
        dgc_edge_csr<<<(NE + 255) / 256, 256, 0, stream>>>(
            x, ef, src, dst, W1, b1, W2, b2, msg, pos, deg);
        dgc_scan<<<1, 1024, 0, stream>>>(deg, offs, NN);
        dgc_scatter<<<(NE + 255) / 256, 256, 0, stream>>>(dst, pos, offs, eidx);
        dgc_gather<<<(NN * FOUT + 255) / 256, 256, 0, stream>>>(
            msg, offs, eidx, x, bias, out);
    }
}

// Round 14
// 211.056 us; speedup vs baseline: 1.2468x; 1.0125x over previous
//
#include <hip/hip_runtime.h>

#define NN 50000
#define NE 500000
#define FIN 16
#define FOUT 16
#define HID 64
#define TROW 1040   // ushorts/node: [jp<32][o<16][2] f16 pairs (j=2jp,2jp+1) + b2 row f16 @1024

typedef unsigned int  uint;
typedef unsigned short ushort;
typedef __fp16 h2 __attribute__((ext_vector_type(2)));   // matches cvt_pkrtz/fdot2 builtin type

__device__ __forceinline__ ushort f2h(float f) {            // f32 -> f16 bits
    union { __fp16 h; ushort s; } v; v.h = (__fp16)f; return v.s;
}
__device__ __forceinline__ h2 u2h2(uint u) {                // uint -> 2xf16
    union { uint u; h2 h; } v; v.u = u; return v.h;
}
__device__ __forceinline__ float h2lo(uint u) {
    union { ushort s; __fp16 h; } v; v.s = (ushort)(u & 0xffffu); return (float)v.h;
}
__device__ __forceinline__ float h2hi(uint u) {
    union { ushort s; __fp16 h; } v; v.s = (ushort)(u >> 16); return (float)v.h;
}

// ===========================================================================
// MAIN PATH. Round-13 lesson: fdot2 cut VALU 45->29% but time stuck at 72us:
// memory-latency bound at occ 32% (2-edge/thread grid = 977 blocks = <4
// blocks/CU, 48% occupancy CEILING). Round-14: back to 1 edge/thread (1954
// blocks, ~95% occ ceiling, TLP>ILP now that VALU is thin), keep f16+fdot2.
// ===========================================================================

// blocks [0,1954): count ranks+degrees. blocks [1954,+65): W2R/W1T transforms.
__global__ __launch_bounds__(256) void count_w2r(
    const int* __restrict__ src, const int* __restrict__ dst,
    int* __restrict__ deg_s, int* __restrict__ pos_s,
    int* __restrict__ deg_d, int* __restrict__ pos_d,
    const float* __restrict__ W2, const float* __restrict__ b2,
    const float* __restrict__ W1, float* __restrict__ W2R,
    float* __restrict__ W1T)
{
    const int nbc = (NE + 255) / 256;
    if ((int)blockIdx.x < nbc) {
        const int e = blockIdx.x * 256 + threadIdx.x;
        if (e < NE) {
            pos_s[e] = atomicAdd(deg_s + src[e], 1);
            pos_d[e] = atomicAdd(deg_d + dst[e], 1);
        }
    } else {
        const int t = (blockIdx.x - nbc) * 256 + threadIdx.x;
        if (t < 64 * 16) {
            const int j = t >> 4, i = t & 15;
            W1T[t] = W1[i * HID + j];          // W1T[j][i] = W1[i][j]
        }
        if (t < 65 * 256) {
            const int j = t >> 8;
            const int col = t & 255;           // col = i*16 + o
            const int i = col >> 4, o = col & 15;
            const float v = (j < 64) ? W2[j * 256 + col] : b2[col];
            W2R[j * 256 + o * 16 + i] = v;     // W2R[j][o][i]
        }
    }
}

// two independent exclusive scans (block 0: A, block 1: B), n=NN each
__global__ __launch_bounds__(1024) void dgc_scan2(
    const int* __restrict__ degA, int* __restrict__ offA,
    const int* __restrict__ degB, int* __restrict__ offB)
{
    const int* __restrict__ deg = blockIdx.x ? degB : degA;
    int* __restrict__ offs      = blockIdx.x ? offB : offA;
    __shared__ int wsum[16];
    const int tid = threadIdx.x;
    const int lane = tid & 63;
    const int wid = tid >> 6;
    int carry = 0;
    for (int base = 0; base < NN; base += 1024) {
        const int idx = base + tid;
        const int v = (idx < NN) ? deg[idx] : 0;
        int s = v;
        #pragma unroll
        for (int d = 1; d < 64; d <<= 1) {
            int t = __shfl_up(s, d, 64);
            if (lane >= d) s += t;
        }
        if (lane == 63) wsum[wid] = s;
        __syncthreads();
        if (wid == 0 && lane < 16) {
            int w = wsum[lane];
            #pragma unroll
            for (int d = 1; d < 16; d <<= 1) {
                int t = __shfl_up(w, d, 64);
                if (lane >= d) w += t;
            }
            wsum[lane] = w;
        }
        __syncthreads();
        const int wpre = (wid == 0) ? 0 : wsum[wid - 1];
        if (idx < NN) offs[idx] = carry + wpre + (s - v);
        carry += wsum[15];
        __syncthreads();
    }
    if (tid == 0) offs[NN] = carry;
}

// blocks [0,1954): scatter edge ids into src-CSR. blocks [1954,+2048): tprep
// (thread (jt,o) owns 4 W2R rows in regs; j-pair-interleaved f16 stores).
__global__ __launch_bounds__(256) void scatter_tprep(
    const int* __restrict__ src, const int* __restrict__ pos_s,
    const int* __restrict__ offs_s, int* __restrict__ eidx_s,
    const float* __restrict__ x, const float* __restrict__ W2R,
    ushort* __restrict__ T)
{
    const int nbs = (NE + 255) / 256;
    if ((int)blockIdx.x < nbs) {
        const int e = blockIdx.x * 256 + threadIdx.x;
        if (e < NE) eidx_s[offs_s[src[e]] + pos_s[e]] = e;
        return;
    }
    const int bid = blockIdx.x - nbs;      // 0..2047
    const int tid = threadIdx.x;
    const int jt = tid >> 4, o = tid & 15;
    // element (j,o) lives at ushort offset (j>>1)*32 + o*2 + (j&1); for
    // j = jt+16k that is off0 + 256k with off0 below (same coalescing as r11).
    const int off0 = (jt >> 1) * 32 + o * 2 + (jt & 1);

    float w0[16], w1[16], w2[16], w3[16];
    {
        const float4* p0 = reinterpret_cast<const float4*>(W2R + (jt     ) * 256 + o * 16);
        const float4* p1 = reinterpret_cast<const float4*>(W2R + (jt + 16) * 256 + o * 16);
        const float4* p2 = reinterpret_cast<const float4*>(W2R + (jt + 32) * 256 + o * 16);
        const float4* p3 = reinterpret_cast<const float4*>(W2R + (jt + 48) * 256 + o * 16);
        #pragma unroll
        for (int q = 0; q < 4; ++q) {
            float4 a = p0[q]; w0[4*q]=a.x; w0[4*q+1]=a.y; w0[4*q+2]=a.z; w0[4*q+3]=a.w;
            float4 b = p1[q]; w1[4*q]=b.x; w1[4*q+1]=b.y; w1[4*q+2]=b.z; w1[4*q+3]=b.w;
            float4 c = p2[q]; w2[4*q]=c.x; w2[4*q+1]=c.y; w2[4*q+2]=c.z; w2[4*q+3]=c.w;
            float4 d = p3[q]; w3[4*q]=d.x; w3[4*q+1]=d.y; w3[4*q+2]=d.z; w3[4*q+3]=d.w;
        }
    }
    float wb[16];
    if (jt == 0) {
        const float4* pb = reinterpret_cast<const float4*>(W2R + 64 * 256 + o * 16);
        #pragma unroll
        for (int q = 0; q < 4; ++q) {
            float4 a = pb[q]; wb[4*q]=a.x; wb[4*q+1]=a.y; wb[4*q+2]=a.z; wb[4*q+3]=a.w;
        }
    }

    for (int n = bid; n < NN; n += 2048) {
        float xr[16];
        {
            const float4* p = reinterpret_cast<const float4*>(x) + (size_t)n * 4;
            float4 a = p[0], b = p[1], c = p[2], d = p[3];
            xr[0]=a.x; xr[1]=a.y; xr[2]=a.z;  xr[3]=a.w;
            xr[4]=b.x; xr[5]=b.y; xr[6]=b.z;  xr[7]=b.w;
            xr[8]=c.x; xr[9]=c.y; xr[10]=c.z; xr[11]=c.w;
            xr[12]=d.x; xr[13]=d.y; xr[14]=d.z; xr[15]=d.w;
        }
        ushort* tw = T + (size_t)n * TROW;

        float s0 = xr[0]*w0[0], s1 = xr[0]*w1[0], s2 = xr[0]*w2[0], s3 = xr[0]*w3[0];
        #pragma unroll
        for (int i = 1; i < 16; ++i) {
            s0 = fmaf(xr[i], w0[i], s0);
            s1 = fmaf(xr[i], w1[i], s1);
            s2 = fmaf(xr[i], w2[i], s2);
            s3 = fmaf(xr[i], w3[i], s3);
        }
        tw[off0]       = f2h(s0);
        tw[off0 + 256] = f2h(s1);
        tw[off0 + 512] = f2h(s2);
        tw[off0 + 768] = f2h(s3);
        if (jt == 0) {
            float sb = xr[0]*wb[0];
            #pragma unroll
            for (int i = 1; i < 16; ++i) sb = fmaf(xr[i], wb[i], sb);
            tw[1024 + o] = f2h(sb);
        }
    }
}

// edge_msg6: 1 edge/thread (max TLP now that fdot2 thinned VALU); f16 j-pair
// T rows consumed via v_dot2_f32_f16. No atomics; direct dst-slot write.
__global__ __launch_bounds__(256) void edge_msg6(
    const int* __restrict__ eidx_s, const int* __restrict__ src,
    const int* __restrict__ dst, const float* __restrict__ ef,
    const float* __restrict__ W1T, const float* __restrict__ b1,
    const ushort* __restrict__ T, const int* __restrict__ offs_d,
    const int* __restrict__ pos_d, float* __restrict__ msgbuf)
{
    const int k = blockIdx.x * blockDim.x + threadIdx.x;
    if (k >= NE) return;
    const int e = eidx_s[k];
    const int s = src[e];

    float ea[16];
    {
        const float4* p = reinterpret_cast<const float4*>(ef) + (size_t)e * 4;
        float4 a = p[0], b = p[1], c = p[2], d = p[3];
        ea[0]=a.x; ea[1]=a.y; ea[2]=a.z;  ea[3]=a.w;
        ea[4]=b.x; ea[5]=b.y; ea[6]=b.z;  ea[7]=b.w;
        ea[8]=c.x; ea[9]=c.y; ea[10]=c.z; ea[11]=c.w;
        ea[12]=d.x; ea[13]=d.y; ea[14]=d.z; ea[15]=d.w;
    }

    const ushort* tr = T + (size_t)s * TROW;

    float m0[16];
    {   // b2 row (f16 @ offset 1024): one-time unpack
        uint4 a = *reinterpret_cast<const uint4*>(tr + 1024);
        uint4 b = *reinterpret_cast<const uint4*>(tr + 1032);
        m0[0]=h2lo(a.x);  m0[1]=h2hi(a.x);  m0[2]=h2lo(a.y);  m0[3]=h2hi(a.y);
        m0[4]=h2lo(a.z);  m0[5]=h2hi(a.z);  m0[6]=h2lo(a.w);  m0[7]=h2hi(a.w);
        m0[8]=h2lo(b.x);  m0[9]=h2hi(b.x);  m0[10]=h2lo(b.y); m0[11]=h2hi(b.y);
        m0[12]=h2lo(b.z); m0[13]=h2hi(b.z); m0[14]=h2lo(b.w); m0[15]=h2hi(b.w);
    }

    for (int jp = 0; jp < 32; ++jp) {
        const float* __restrict__ wr = W1T + jp * 32;   // rows j0=2jp, j1=2jp+1
        float h0a = b1[2 * jp], h0b = b1[2 * jp + 1];
        #pragma unroll
        for (int i = 0; i < 16; ++i) {
            h0a = fmaf(ea[i], wr[i], h0a);
            h0b = fmaf(ea[i], wr[16 + i], h0b);
        }
        h0a = fmaxf(h0a, 0.f); h0b = fmaxf(h0b, 0.f);
        const h2 hp0 = __builtin_amdgcn_cvt_pkrtz(h0a, h0b);

        const uint4 a0 = *reinterpret_cast<const uint4*>(tr + jp * 32);
        const uint4 b0 = *reinterpret_cast<const uint4*>(tr + jp * 32 + 8);
        const uint4 c0 = *reinterpret_cast<const uint4*>(tr + jp * 32 + 16);
        const uint4 d0 = *reinterpret_cast<const uint4*>(tr + jp * 32 + 24);

        m0[0]  = __builtin_amdgcn_fdot2(hp0, u2h2(a0.x), m0[0],  false);
        m0[1]  = __builtin_amdgcn_fdot2(hp0, u2h2(a0.y), m0[1],  false);
        m0[2]  = __builtin_amdgcn_fdot2(hp0, u2h2(a0.z), m0[2],  false);
        m0[3]  = __builtin_amdgcn_fdot2(hp0, u2h2(a0.w), m0[3],  false);
        m0[4]  = __builtin_amdgcn_fdot2(hp0, u2h2(b0.x), m0[4],  false);
        m0[5]  = __builtin_amdgcn_fdot2(hp0, u2h2(b0.y), m0[5],  false);
        m0[6]  = __builtin_amdgcn_fdot2(hp0, u2h2(b0.z), m0[6],  false);
        m0[7]  = __builtin_amdgcn_fdot2(hp0, u2h2(b0.w), m0[7],  false);
        m0[8]  = __builtin_amdgcn_fdot2(hp0, u2h2(c0.x), m0[8],  false);
        m0[9]  = __builtin_amdgcn_fdot2(hp0, u2h2(c0.y), m0[9],  false);
        m0[10] = __builtin_amdgcn_fdot2(hp0, u2h2(c0.z), m0[10], false);
        m0[11] = __builtin_amdgcn_fdot2(hp0, u2h2(c0.w), m0[11], false);
        m0[12] = __builtin_amdgcn_fdot2(hp0, u2h2(d0.x), m0[12], false);
        m0[13] = __builtin_amdgcn_fdot2(hp0, u2h2(d0.y), m0[13], false);
        m0[14] = __builtin_amdgcn_fdot2(hp0, u2h2(d0.z), m0[14], false);
        m0[15] = __builtin_amdgcn_fdot2(hp0, u2h2(d0.w), m0[15], false);
    }

    const int d = dst[e];
    const int slot = offs_d[d] + pos_d[e];
    float4* mr = reinterpret_cast<float4*>(msgbuf + (size_t)slot * 16);
    mr[0] = make_float4(m0[0], m0[1], m0[2], m0[3]);
    mr[1] = make_float4(m0[4], m0[5], m0[6], m0[7]);
    mr[2] = make_float4(m0[8], m0[9], m0[10], m0[11]);
    mr[3] = make_float4(m0[12], m0[13], m0[14], m0[15]);
}

// gather_mean3: thread = (node, o-quad); float4 reads/writes, 4 outputs/thread
__global__ __launch_bounds__(256) void gather_mean3(
    const float* __restrict__ msgbuf, const int* __restrict__ offs_d,
    const float* __restrict__ x, const float* __restrict__ bias,
    float* __restrict__ out)
{
    const int t = blockIdx.x * blockDim.x + threadIdx.x;
    if (t >= NN * 4) return;
    const int n = t >> 2;
    const int oq = t & 3;
    const int beg = offs_d[n], end = offs_d[n + 1];
    float4 s = make_float4(0.f, 0.f, 0.f, 0.f);
    for (int k = beg; k < end; ++k) {
        const float4 v = *reinterpret_cast<const float4*>(msgbuf + (size_t)k * 16 + oq * 4);
        s.x += v.x; s.y += v.y; s.z += v.z; s.w += v.w;
    }
    const int d = end - beg;
    float4 r;
    if (d > 0) {
        const float inv = 1.f / (float)d;
        r = make_float4(s.x * inv, s.y * inv, s.z * inv, s.w * inv);
    } else {
        r = *reinterpret_cast<const float4*>(x + (size_t)n * 16 + oq * 4);
    }
    const float4 bv = *reinterpret_cast<const float4*>(bias + oq * 4);
    r.x += bv.x; r.y += bv.y; r.z += bv.z; r.w += bv.w;
    *reinterpret_cast<float4*>(out + (size_t)n * 16 + oq * 4) = r;
}

// ===========================================================================
// FALLBACK (round-2 proven path, ~36.4 MB ws)
// ===========================================================================
__global__ __launch_bounds__(1024) void dgc_scan(
    const int* __restrict__ deg, int* __restrict__ offs, int n)
{
    __shared__ int wsum[16];
    const int tid = threadIdx.x;
    const int lane = tid & 63;
    const int wid = tid >> 6;
    int carry = 0;
    for (int base = 0; base < n; base += 1024) {
        const int idx = base + tid;
        const int v = (idx < n) ? deg[idx] : 0;
        int s = v;
        #pragma unroll
        for (int d = 1; d < 64; d <<= 1) {
            int t = __shfl_up(s, d, 64);
            if (lane >= d) s += t;
        }
        if (lane == 63) wsum[wid] = s;
        __syncthreads();
        if (wid == 0 && lane < 16) {
            int w = wsum[lane];
            #pragma unroll
            for (int d = 1; d < 16; d <<= 1) {
                int t = __shfl_up(w, d, 64);
                if (lane >= d) w += t;
            }
            wsum[lane] = w;
        }
        __syncthreads();
        const int wpre = (wid == 0) ? 0 : wsum[wid - 1];
        if (idx < n) offs[idx] = carry + wpre + (s - v);
        carry += wsum[15];
        __syncthreads();
    }
    if (tid == 0) offs[n] = carry;
}

__global__ __launch_bounds__(256) void dgc_edge_csr(
    const float* __restrict__ x, const float* __restrict__ ef,
    const int* __restrict__ src, const int* __restrict__ dst,
    const float* __restrict__ W1, const float* __restrict__ b1,
    const float* __restrict__ W2, const float* __restrict__ b2,
    float* __restrict__ msg, int* __restrict__ pos, int* __restrict__ deg)
{
    const int e = blockIdx.x * blockDim.x + threadIdx.x;
    if (e >= NE) return;
    float efv[16];
    {
        const float4* p = reinterpret_cast<const float4*>(ef) + (size_t)e * 4;
        float4 a = p[0], b = p[1], c = p[2], d = p[3];
        efv[0]=a.x; efv[1]=a.y; efv[2]=a.z;  efv[3]=a.w;
        efv[4]=b.x; efv[5]=b.y; efv[6]=b.z;  efv[7]=b.w;
        efv[8]=c.x; efv[9]=c.y; efv[10]=c.z; efv[11]=c.w;
        efv[12]=d.x; efv[13]=d.y; efv[14]=d.z; efv[15]=d.w;
    }
    const int s = src[e];
    float xs[16];
    {
        const float4* p = reinterpret_cast<const float4*>(x) + (size_t)s * 4;
        float4 a = p[0], b = p[1], c = p[2], d = p[3];
        xs[0]=a.x; xs[1]=a.y; xs[2]=a.z;  xs[3]=a.w;
        xs[4]=b.x; xs[5]=b.y; xs[6]=b.z;  xs[7]=b.w;
        xs[8]=c.x; xs[9]=c.y; xs[10]=c.z; xs[11]=c.w;
        xs[12]=d.x; xs[13]=d.y; xs[14]=d.z; xs[15]=d.w;
    }
    float m[16];
    #pragma unroll
    for (int o = 0; o < 16; ++o) m[o] = 0.f;
    #pragma unroll
    for (int i = 0; i < 16; ++i) {
        const float xi = xs[i];
        #pragma unroll
        for (int o = 0; o < 16; ++o) m[o] = fmaf(xi, b2[i * 16 + o], m[o]);
    }
    for (int j = 0; j < HID; ++j) {
        float hj = b1[j];
        #pragma unroll
        for (int i = 0; i < 16; ++i) hj = fmaf(efv[i], W1[i * HID + j], hj);
        hj = fmaxf(hj, 0.f);
        const float* __restrict__ w2r = W2 + (size_t)j * 256;
        float t[16];
        #pragma unroll
        for (int o = 0; o < 16; ++o) t[o] = 0.f;
        #pragma unroll
        for (int i = 0; i < 16; ++i) {
            const float xi = xs[i];
            #pragma unroll
            for (int o = 0; o < 16; ++o) t[o] = fmaf(xi, w2r[i * 16 + o], t[o]);
        }
        #pragma unroll
        for (int o = 0; o < 16; ++o) m[o] = fmaf(hj, t[o], m[o]);
    }
    float4* mr = reinterpret_cast<float4*>(msg + (size_t)e * 16);
    mr[0] = make_float4(m[0], m[1], m[2], m[3]);
    mr[1] = make_float4(m[4], m[5], m[6], m[7]);
    mr[2] = make_float4(m[8], m[9], m[10], m[11]);
    mr[3] = make_float4(m[12], m[13], m[14], m[15]);
    pos[e] = atomicAdd(deg + dst[e], 1);
}

__global__ __launch_bounds__(256) void dgc_scatter(
    const int* __restrict__ dst, const int* __restrict__ pos,
    const int* __restrict__ offs, int* __restrict__ eidx)
{
    const int e = blockIdx.x * blockDim.x + threadIdx.x;
    if (e >= NE) return;
    eidx[offs[dst[e]] + pos[e]] = e;
}

__global__ __launch_bounds__(256) void dgc_gather(
    const float* __restrict__ msg, const int* __restrict__ offs,
    const int* __restrict__ eidx, const float* __restrict__ x,
    const float* __restrict__ bias, float* __restrict__ out)
{
    const int t = blockIdx.x * blockDim.x + threadIdx.x;
    if (t >= NN * FOUT) return;
    const int n = t >> 4;
    const int o = t & 15;
    const int beg = offs[n], end = offs[n + 1];
    float s = 0.f;
    for (int k = beg; k < end; ++k)
        s += msg[(size_t)eidx[k] * 16 + o];
    const int d = end - beg;
    const float v = (d > 0) ? (s / (float)d) : x[t];
    out[t] = v + bias[o];
}

extern "C" void kernel_launch(void* const* d_in, const int* in_sizes, int n_in,
                              void* d_out, int out_size, void* d_ws, size_t ws_size,
                              hipStream_t stream) {
    const float* x    = (const float*)d_in[0];
    const float* ef   = (const float*)d_in[1];
    const int*   src  = (const int*)d_in[2];
    const int*   dst  = (const int*)d_in[3];
    const float* W1   = (const float*)d_in[4];
    const float* b1   = (const float*)d_in[5];
    const float* W2   = (const float*)d_in[6];
    const float* b2   = (const float*)d_in[7];
    const float* bias = (const float*)d_in[8];
    float* out = (float*)d_out;

    // main-path ws layout
    ushort* T      = (ushort*)d_ws;                       // NN*TROW f16 (104 MB)
    float*  msgbuf = (float*)(T + (size_t)NN * TROW);     // NE*16 f32   (32 MB)
    float*  W2R    = msgbuf + (size_t)NE * 16;            // 65*256
    float*  W1T    = W2R + 65 * 256;                      // 64*16
    int*    deg_s  = (int*)(W1T + 64 * 16);               // NN
    int*    deg_d  = deg_s + NN;                          // NN
    int*    offs_s = deg_d + NN;                          // NN+1
    int*    offs_d = offs_s + NN + 1;                     // NN+1
    int*    pos_s  = offs_d + NN + 1;                     // NE
    int*    pos_d  = pos_s + NE;                          // NE
    int*    eidx_s = pos_d + NE;                          // NE
    const size_t needed =
        (size_t)NN * TROW * 2 +
        ((size_t)NE * 16 + 65 * 256 + 64 * 16) * 4 +
        ((size_t)2 * NN + 2 * (NN + 1) + (size_t)3 * NE) * 4;

    const int nbc = (NE + 255) / 256;   // 1954

    if (ws_size >= needed) {
        hipMemsetAsync(deg_s, 0, (size_t)2 * NN * sizeof(int), stream);
        count_w2r<<<nbc + 65, 256, 0, stream>>>(
            src, dst, deg_s, pos_s, deg_d, pos_d, W2, b2, W1, W2R, W1T);
        dgc_scan2<<<2, 1024, 0, stream>>>(deg_s, offs_s, deg_d, offs_d);
        scatter_tprep<<<nbc + 2048, 256, 0, stream>>>(
            src, pos_s, offs_s, eidx_s, x, W2R, T);
        edge_msg6<<<nbc, 256, 0, stream>>>(
            eidx_s, src, dst, ef, W1T, b1, T, offs_d, pos_d, msgbuf);
        gather_mean3<<<(NN * 4 + 255) / 256, 256, 0, stream>>>(
            msgbuf, offs_d, x, bias, out);
    } else {
        // round-2 fallback
        float* msg  = (float*)d_ws;
        int*   deg  = (int*)(msg + (size_t)NE * 16);
        int*   offs = deg + NN;
        int*   pos  = offs + NN + 1;
        int*   eidx = pos + NE;
        hipMemsetAsync(deg, 0, (size_t)NN * sizeof(int), stream);
        dgc_edge_csr<<<(NE + 255) / 256, 256, 0, stream>>>(
            x, ef, src, dst, W1, b1, W2, b2, msg, pos, deg);
        dgc_scan<<<1, 1024, 0, stream>>>(deg, offs, NN);
        dgc_scatter<<<(NE + 255) / 256, 256, 0, stream>>>(dst, pos, offs, eidx);
        dgc_gather<<<(NN * FOUT + 255) / 256, 256, 0, stream>>>(
            msg, offs, eidx, x, bias, out);
    }
}

// Round 15
// 210.864 us; speedup vs baseline: 1.2479x; 1.0009x over previous
//
#include <hip/hip_runtime.h>

#define NN 50000
#define NE 500000
#define FIN 16
#define FOUT 16
#define HID 64
#define TROW 1040   // ushorts/node: [jp<32][o<16][2] f16 pairs (j=2jp,2jp+1) + b2 row f16 @1024

typedef unsigned int  uint;
typedef unsigned short ushort;
typedef __fp16 h2 __attribute__((ext_vector_type(2)));   // matches cvt_pkrtz/fdot2 builtin type

__device__ __forceinline__ ushort f2h(float f) {            // f32 -> f16 bits
    union { __fp16 h; ushort s; } v; v.h = (__fp16)f; return v.s;
}
__device__ __forceinline__ h2 u2h2(uint u) {                // uint -> 2xf16
    union { uint u; h2 h; } v; v.u = u; return v.h;
}
__device__ __forceinline__ float h2lo(uint u) {
    union { ushort s; __fp16 h; } v; v.s = (ushort)(u & 0xffffu); return (float)v.h;
}
__device__ __forceinline__ float h2hi(uint u) {
    union { ushort s; __fp16 h; } v; v.s = (ushort)(u >> 16); return (float)v.h;
}

// ===========================================================================
// MAIN PATH. Round-14 lesson: occupancy 32->57% didn't move the edge kernel
// (70us): VGPR=28 shows the compiler keeps only ONE jp's T loads in flight ->
// per-jp serialized load/L2-latency/compute. Round-15: explicit software
// pipeline — prefetch jp+1's four uint4 into named regs before consuming jp
// (b2 row @1024 makes the jp=31 prefetch in-bounds, no branch). +16 VGPR.
// ===========================================================================

// blocks [0,1954): count ranks+degrees. blocks [1954,+65): W2R/W1T transforms.
__global__ __launch_bounds__(256) void count_w2r(
    const int* __restrict__ src, const int* __restrict__ dst,
    int* __restrict__ deg_s, int* __restrict__ pos_s,
    int* __restrict__ deg_d, int* __restrict__ pos_d,
    const float* __restrict__ W2, const float* __restrict__ b2,
    const float* __restrict__ W1, float* __restrict__ W2R,
    float* __restrict__ W1T)
{
    const int nbc = (NE + 255) / 256;
    if ((int)blockIdx.x < nbc) {
        const int e = blockIdx.x * 256 + threadIdx.x;
        if (e < NE) {
            pos_s[e] = atomicAdd(deg_s + src[e], 1);
            pos_d[e] = atomicAdd(deg_d + dst[e], 1);
        }
    } else {
        const int t = (blockIdx.x - nbc) * 256 + threadIdx.x;
        if (t < 64 * 16) {
            const int j = t >> 4, i = t & 15;
            W1T[t] = W1[i * HID + j];          // W1T[j][i] = W1[i][j]
        }
        if (t < 65 * 256) {
            const int j = t >> 8;
            const int col = t & 255;           // col = i*16 + o
            const int i = col >> 4, o = col & 15;
            const float v = (j < 64) ? W2[j * 256 + col] : b2[col];
            W2R[j * 256 + o * 16 + i] = v;     // W2R[j][o][i]
        }
    }
}

// two independent exclusive scans (block 0: A, block 1: B), n=NN each
__global__ __launch_bounds__(1024) void dgc_scan2(
    const int* __restrict__ degA, int* __restrict__ offA,
    const int* __restrict__ degB, int* __restrict__ offB)
{
    const int* __restrict__ deg = blockIdx.x ? degB : degA;
    int* __restrict__ offs      = blockIdx.x ? offB : offA;
    __shared__ int wsum[16];
    const int tid = threadIdx.x;
    const int lane = tid & 63;
    const int wid = tid >> 6;
    int carry = 0;
    for (int base = 0; base < NN; base += 1024) {
        const int idx = base + tid;
        const int v = (idx < NN) ? deg[idx] : 0;
        int s = v;
        #pragma unroll
        for (int d = 1; d < 64; d <<= 1) {
            int t = __shfl_up(s, d, 64);
            if (lane >= d) s += t;
        }
        if (lane == 63) wsum[wid] = s;
        __syncthreads();
        if (wid == 0 && lane < 16) {
            int w = wsum[lane];
            #pragma unroll
            for (int d = 1; d < 16; d <<= 1) {
                int t = __shfl_up(w, d, 64);
                if (lane >= d) w += t;
            }
            wsum[lane] = w;
        }
        __syncthreads();
        const int wpre = (wid == 0) ? 0 : wsum[wid - 1];
        if (idx < NN) offs[idx] = carry + wpre + (s - v);
        carry += wsum[15];
        __syncthreads();
    }
    if (tid == 0) offs[NN] = carry;
}

// blocks [0,1954): scatter edge ids into src-CSR. blocks [1954,+2048): tprep
// (thread (jt,o) owns 4 W2R rows in regs; j-pair-interleaved f16 stores).
__global__ __launch_bounds__(256) void scatter_tprep(
    const int* __restrict__ src, const int* __restrict__ pos_s,
    const int* __restrict__ offs_s, int* __restrict__ eidx_s,
    const float* __restrict__ x, const float* __restrict__ W2R,
    ushort* __restrict__ T)
{
    const int nbs = (NE + 255) / 256;
    if ((int)blockIdx.x < nbs) {
        const int e = blockIdx.x * 256 + threadIdx.x;
        if (e < NE) eidx_s[offs_s[src[e]] + pos_s[e]] = e;
        return;
    }
    const int bid = blockIdx.x - nbs;      // 0..2047
    const int tid = threadIdx.x;
    const int jt = tid >> 4, o = tid & 15;
    // element (j,o) lives at ushort offset (j>>1)*32 + o*2 + (j&1); for
    // j = jt+16k that is off0 + 256k with off0 below.
    const int off0 = (jt >> 1) * 32 + o * 2 + (jt & 1);

    float w0[16], w1[16], w2[16], w3[16];
    {
        const float4* p0 = reinterpret_cast<const float4*>(W2R + (jt     ) * 256 + o * 16);
        const float4* p1 = reinterpret_cast<const float4*>(W2R + (jt + 16) * 256 + o * 16);
        const float4* p2 = reinterpret_cast<const float4*>(W2R + (jt + 32) * 256 + o * 16);
        const float4* p3 = reinterpret_cast<const float4*>(W2R + (jt + 48) * 256 + o * 16);
        #pragma unroll
        for (int q = 0; q < 4; ++q) {
            float4 a = p0[q]; w0[4*q]=a.x; w0[4*q+1]=a.y; w0[4*q+2]=a.z; w0[4*q+3]=a.w;
            float4 b = p1[q]; w1[4*q]=b.x; w1[4*q+1]=b.y; w1[4*q+2]=b.z; w1[4*q+3]=b.w;
            float4 c = p2[q]; w2[4*q]=c.x; w2[4*q+1]=c.y; w2[4*q+2]=c.z; w2[4*q+3]=c.w;
            float4 d = p3[q]; w3[4*q]=d.x; w3[4*q+1]=d.y; w3[4*q+2]=d.z; w3[4*q+3]=d.w;
        }
    }
    float wb[16];
    if (jt == 0) {
        const float4* pb = reinterpret_cast<const float4*>(W2R + 64 * 256 + o * 16);
        #pragma unroll
        for (int q = 0; q < 4; ++q) {
            float4 a = pb[q]; wb[4*q]=a.x; wb[4*q+1]=a.y; wb[4*q+2]=a.z; wb[4*q+3]=a.w;
        }
    }

    for (int n = bid; n < NN; n += 2048) {
        float xr[16];
        {
            const float4* p = reinterpret_cast<const float4*>(x) + (size_t)n * 4;
            float4 a = p[0], b = p[1], c = p[2], d = p[3];
            xr[0]=a.x; xr[1]=a.y; xr[2]=a.z;  xr[3]=a.w;
            xr[4]=b.x; xr[5]=b.y; xr[6]=b.z;  xr[7]=b.w;
            xr[8]=c.x; xr[9]=c.y; xr[10]=c.z; xr[11]=c.w;
            xr[12]=d.x; xr[13]=d.y; xr[14]=d.z; xr[15]=d.w;
        }
        ushort* tw = T + (size_t)n * TROW;

        float s0 = xr[0]*w0[0], s1 = xr[0]*w1[0], s2 = xr[0]*w2[0], s3 = xr[0]*w3[0];
        #pragma unroll
        for (int i = 1; i < 16; ++i) {
            s0 = fmaf(xr[i], w0[i], s0);
            s1 = fmaf(xr[i], w1[i], s1);
            s2 = fmaf(xr[i], w2[i], s2);
            s3 = fmaf(xr[i], w3[i], s3);
        }
        tw[off0]       = f2h(s0);
        tw[off0 + 256] = f2h(s1);
        tw[off0 + 512] = f2h(s2);
        tw[off0 + 768] = f2h(s3);
        if (jt == 0) {
            float sb = xr[0]*wb[0];
            #pragma unroll
            for (int i = 1; i < 16; ++i) sb = fmaf(xr[i], wb[i], sb);
            tw[1024 + o] = f2h(sb);
        }
    }
}

// edge_msg7: 1 edge/thread, f16 j-pair T rows via fdot2, SOFTWARE-PIPELINED:
// jp+1's 4 uint4 loaded into named regs before jp's fdot2 consume. jp=31
// prefetch reads the b2 row (in-bounds by construction).
__global__ __launch_bounds__(256) void edge_msg7(
    const int* __restrict__ eidx_s, const int* __restrict__ src,
    const int* __restrict__ dst, const float* __restrict__ ef,
    const float* __restrict__ W1T, const float* __restrict__ b1,
    const ushort* __restrict__ T, const int* __restrict__ offs_d,
    const int* __restrict__ pos_d, float* __restrict__ msgbuf)
{
    const int k = blockIdx.x * blockDim.x + threadIdx.x;
    if (k >= NE) return;
    const int e = eidx_s[k];
    const int s = src[e];

    const ushort* tr = T + (size_t)s * TROW;
    const uint4* tq = reinterpret_cast<const uint4*>(tr);   // 8 ushorts per uint4

    // issue first-jp loads ASAP
    uint4 A0 = tq[0], A1 = tq[1], A2 = tq[2], A3 = tq[3];

    float ea[16];
    {
        const float4* p = reinterpret_cast<const float4*>(ef) + (size_t)e * 4;
        float4 a = p[0], b = p[1], c = p[2], d = p[3];
        ea[0]=a.x; ea[1]=a.y; ea[2]=a.z;  ea[3]=a.w;
        ea[4]=b.x; ea[5]=b.y; ea[6]=b.z;  ea[7]=b.w;
        ea[8]=c.x; ea[9]=c.y; ea[10]=c.z; ea[11]=c.w;
        ea[12]=d.x; ea[13]=d.y; ea[14]=d.z; ea[15]=d.w;
    }

    float m0[16];
    {   // b2 row (f16 @ ushort offset 1024 = uint4 index 128,129)
        uint4 a = tq[128];
        uint4 b = tq[129];
        m0[0]=h2lo(a.x);  m0[1]=h2hi(a.x);  m0[2]=h2lo(a.y);  m0[3]=h2hi(a.y);
        m0[4]=h2lo(a.z);  m0[5]=h2hi(a.z);  m0[6]=h2lo(a.w);  m0[7]=h2hi(a.w);
        m0[8]=h2lo(b.x);  m0[9]=h2hi(b.x);  m0[10]=h2lo(b.y); m0[11]=h2hi(b.y);
        m0[12]=h2lo(b.z); m0[13]=h2hi(b.z); m0[14]=h2lo(b.w); m0[15]=h2hi(b.w);
    }

    for (int jp = 0; jp < 32; ++jp) {
        // prefetch next jp (jp=31 -> reads b2 row, in-bounds, discarded)
        const int nb = (jp + 1) << 2;
        uint4 B0 = tq[nb], B1 = tq[nb + 1], B2 = tq[nb + 2], B3 = tq[nb + 3];

        const float* __restrict__ wr = W1T + jp * 32;   // rows j0=2jp, j1=2jp+1
        float h0a = b1[2 * jp], h0b = b1[2 * jp + 1];
        #pragma unroll
        for (int i = 0; i < 16; ++i) {
            h0a = fmaf(ea[i], wr[i], h0a);
            h0b = fmaf(ea[i], wr[16 + i], h0b);
        }
        h0a = fmaxf(h0a, 0.f); h0b = fmaxf(h0b, 0.f);
        const h2 hp0 = __builtin_amdgcn_cvt_pkrtz(h0a, h0b);

        m0[0]  = __builtin_amdgcn_fdot2(hp0, u2h2(A0.x), m0[0],  false);
        m0[1]  = __builtin_amdgcn_fdot2(hp0, u2h2(A0.y), m0[1],  false);
        m0[2]  = __builtin_amdgcn_fdot2(hp0, u2h2(A0.z), m0[2],  false);
        m0[3]  = __builtin_amdgcn_fdot2(hp0, u2h2(A0.w), m0[3],  false);
        m0[4]  = __builtin_amdgcn_fdot2(hp0, u2h2(A1.x), m0[4],  false);
        m0[5]  = __builtin_amdgcn_fdot2(hp0, u2h2(A1.y), m0[5],  false);
        m0[6]  = __builtin_amdgcn_fdot2(hp0, u2h2(A1.z), m0[6],  false);
        m0[7]  = __builtin_amdgcn_fdot2(hp0, u2h2(A1.w), m0[7],  false);
        m0[8]  = __builtin_amdgcn_fdot2(hp0, u2h2(A2.x), m0[8],  false);
        m0[9]  = __builtin_amdgcn_fdot2(hp0, u2h2(A2.y), m0[9],  false);
        m0[10] = __builtin_amdgcn_fdot2(hp0, u2h2(A2.z), m0[10], false);
        m0[11] = __builtin_amdgcn_fdot2(hp0, u2h2(A2.w), m0[11], false);
        m0[12] = __builtin_amdgcn_fdot2(hp0, u2h2(A3.x), m0[12], false);
        m0[13] = __builtin_amdgcn_fdot2(hp0, u2h2(A3.y), m0[13], false);
        m0[14] = __builtin_amdgcn_fdot2(hp0, u2h2(A3.z), m0[14], false);
        m0[15] = __builtin_amdgcn_fdot2(hp0, u2h2(A3.w), m0[15], false);

        A0 = B0; A1 = B1; A2 = B2; A3 = B3;
    }

    const int d = dst[e];
    const int slot = offs_d[d] + pos_d[e];
    float4* mr = reinterpret_cast<float4*>(msgbuf + (size_t)slot * 16);
    mr[0] = make_float4(m0[0], m0[1], m0[2], m0[3]);
    mr[1] = make_float4(m0[4], m0[5], m0[6], m0[7]);
    mr[2] = make_float4(m0[8], m0[9], m0[10], m0[11]);
    mr[3] = make_float4(m0[12], m0[13], m0[14], m0[15]);
}

// gather_mean3: thread = (node, o-quad); float4 reads/writes, 4 outputs/thread
__global__ __launch_bounds__(256) void gather_mean3(
    const float* __restrict__ msgbuf, const int* __restrict__ offs_d,
    const float* __restrict__ x, const float* __restrict__ bias,
    float* __restrict__ out)
{
    const int t = blockIdx.x * blockDim.x + threadIdx.x;
    if (t >= NN * 4) return;
    const int n = t >> 2;
    const int oq = t & 3;
    const int beg = offs_d[n], end = offs_d[n + 1];
    float4 s = make_float4(0.f, 0.f, 0.f, 0.f);
    for (int k = beg; k < end; ++k) {
        const float4 v = *reinterpret_cast<const float4*>(msgbuf + (size_t)k * 16 + oq * 4);
        s.x += v.x; s.y += v.y; s.z += v.z; s.w += v.w;
    }
    const int d = end - beg;
    float4 r;
    if (d > 0) {
        const float inv = 1.f / (float)d;
        r = make_float4(s.x * inv, s.y * inv, s.z * inv, s.w * inv);
    } else {
        r = *reinterpret_cast<const float4*>(x + (size_t)n * 16 + oq * 4);
    }
    const float4 bv = *reinterpret_cast<const float4*>(bias + oq * 4);
    r.x += bv.x; r.y += bv.y; r.z += bv.z; r.w += bv.w;
    *reinterpret_cast<float4*>(out + (size_t)n * 16 + oq * 4) = r;
}

// ===========================================================================
// FALLBACK (round-2 proven path, ~36.4 MB ws)
// ===========================================================================
__global__ __launch_bounds__(1024) void dgc_scan(
    const int* __restrict__ deg, int* __restrict__ offs, int n)
{
    __shared__ int wsum[16];
    const int tid = threadIdx.x;
    const int lane = tid & 63;
    const int wid = tid >> 6;
    int carry = 0;
    for (int base = 0; base < n; base += 1024) {
        const int idx = base + tid;
        const int v = (idx < n) ? deg[idx] : 0;
        int s = v;
        #pragma unroll
        for (int d = 1; d < 64; d <<= 1) {
            int t = __shfl_up(s, d, 64);
            if (lane >= d) s += t;
        }
        if (lane == 63) wsum[wid] = s;
        __syncthreads();
        if (wid == 0 && lane < 16) {
            int w = wsum[lane];
            #pragma unroll
            for (int d = 1; d < 16; d <<= 1) {
                int t = __shfl_up(w, d, 64);
                if (lane >= d) w += t;
            }
            wsum[lane] = w;
        }
        __syncthreads();
        const int wpre = (wid == 0) ? 0 : wsum[wid - 1];
        if (idx < n) offs[idx] = carry + wpre + (s - v);
        carry += wsum[15];
        __syncthreads();
    }
    if (tid == 0) offs[n] = carry;
}

__global__ __launch_bounds__(256) void dgc_edge_csr(
    const float* __restrict__ x, const float* __restrict__ ef,
    const int* __restrict__ src, const int* __restrict__ dst,
    const float* __restrict__ W1, const float* __restrict__ b1,
    const float* __restrict__ W2, const float* __restrict__ b2,
    float* __restrict__ msg, int* __restrict__ pos, int* __restrict__ deg)
{
    const int e = blockIdx.x * blockDim.x + threadIdx.x;
    if (e >= NE) return;
    float efv[16];
    {
        const float4* p = reinterpret_cast<const float4*>(ef) + (size_t)e * 4;
        float4 a = p[0], b = p[1], c = p[2], d = p[3];
        efv[0]=a.x; efv[1]=a.y; efv[2]=a.z;  efv[3]=a.w;
        efv[4]=b.x; efv[5]=b.y; efv[6]=b.z;  efv[7]=b.w;
        efv[8]=c.x; efv[9]=c.y; efv[10]=c.z; efv[11]=c.w;
        efv[12]=d.x; efv[13]=d.y; efv[14]=d.z; efv[15]=d.w;
    }
    const int s = src[e];
    float xs[16];
    {
        const float4* p = reinterpret_cast<const float4*>(x) + (size_t)s * 4;
        float4 a = p[0], b = p[1], c = p[2], d = p[3];
        xs[0]=a.x; xs[1]=a.y; xs[2]=a.z;  xs[3]=a.w;
        xs[4]=b.x; xs[5]=b.y; xs[6]=b.z;  xs[7]=b.w;
        xs[8]=c.x; xs[9]=c.y; xs[10]=c.z; xs[11]=c.w;
        xs[12]=d.x; xs[13]=d.y; xs[14]=d.z; xs[15]=d.w;
    }
    float m[16];
    #pragma unroll
    for (int o = 0; o < 16; ++o) m[o] = 0.f;
    #pragma unroll
    for (int i = 0; i < 16; ++i) {
        const float xi = xs[i];
        #pragma unroll
        for (int o = 0; o < 16; ++o) m[o] = fmaf(xi, b2[i * 16 + o], m[o]);
    }
    for (int j = 0; j < HID; ++j) {
        float hj = b1[j];
        #pragma unroll
        for (int i = 0; i < 16; ++i) hj = fmaf(efv[i], W1[i * HID + j], hj);
        hj = fmaxf(hj, 0.f);
        const float* __restrict__ w2r = W2 + (size_t)j * 256;
        float t[16];
        #pragma unroll
        for (int o = 0; o < 16; ++o) t[o] = 0.f;
        #pragma unroll
        for (int i = 0; i < 16; ++i) {
            const float xi = xs[i];
            #pragma unroll
            for (int o = 0; o < 16; ++o) t[o] = fmaf(xi, w2r[i * 16 + o], t[o]);
        }
        #pragma unroll
        for (int o = 0; o < 16; ++o) m[o] = fmaf(hj, t[o], m[o]);
    }
    float4* mr = reinterpret_cast<float4*>(msg + (size_t)e * 16);
    mr[0] = make_float4(m[0], m[1], m[2], m[3]);
    mr[1] = make_float4(m[4], m[5], m[6], m[7]);
    mr[2] = make_float4(m[8], m[9], m[10], m[11]);
    mr[3] = make_float4(m[12], m[13], m[14], m[15]);
    pos[e] = atomicAdd(deg + dst[e], 1);
}

__global__ __launch_bounds__(256) void dgc_scatter(
    const int* __restrict__ dst, const int* __restrict__ pos,
    const int* __restrict__ offs, int* __restrict__ eidx)
{
    const int e = blockIdx.x * blockDim.x + threadIdx.x;
    if (e >= NE) return;
    eidx[offs[dst[e]] + pos[e]] = e;
}

__global__ __launch_bounds__(256) void dgc_gather(
    const float* __restrict__ msg, const int* __restrict__ offs,
    const int* __restrict__ eidx, const float* __restrict__ x,
    const float* __restrict__ bias, float* __restrict__ out)
{
    const int t = blockIdx.x * blockDim.x + threadIdx.x;
    if (t >= NN * FOUT) return;
    const int n = t >> 4;
    const int o = t & 15;
    const int beg = offs[n], end = offs[n + 1];
    float s = 0.f;
    for (int k = beg; k < end; ++k)
        s += msg[(size_t)eidx[k] * 16 + o];
    const int d = end - beg;
    const float v = (d > 0) ? (s / (float)d) : x[t];
    out[t] = v + bias[o];
}

extern "C" void kernel_launch(void* const* d_in, const int* in_sizes, int n_in,
                              void* d_out, int out_size, void* d_ws, size_t ws_size,
                              hipStream_t stream) {
    const float* x    = (const float*)d_in[0];
    const float* ef   = (const float*)d_in[1];
    const int*   src  = (const int*)d_in[2];
    const int*   dst  = (const int*)d_in[3];
    const float* W1   = (const float*)d_in[4];
    const float* b1   = (const float*)d_in[5];
    const float* W2   = (const float*)d_in[6];
    const float* b2   = (const float*)d_in[7];
    const float* bias = (const float*)d_in[8];
    float* out = (float*)d_out;

    // main-path ws layout
    ushort* T      = (ushort*)d_ws;                       // NN*TROW f16 (104 MB)
    float*  msgbuf = (float*)(T + (size_t)NN * TROW);     // NE*16 f32   (32 MB)
    float*  W2R    = msgbuf + (size_t)NE * 16;            // 65*256
    float*  W1T    = W2R + 65 * 256;                      // 64*16
    int*    deg_s  = (int*)(W1T + 64 * 16);               // NN
    int*    deg_d  = deg_s + NN;                          // NN
    int*    offs_s = deg_d + NN;                          // NN+1
    int*    offs_d = offs_s + NN + 1;                     // NN+1
    int*    pos_s  = offs_d + NN + 1;                     // NE
    int*    pos_d  = pos_s + NE;                          // NE
    int*    eidx_s = pos_d + NE;                          // NE
    const size_t needed =
        (size_t)NN * TROW * 2 +
        ((size_t)NE * 16 + 65 * 256 + 64 * 16) * 4 +
        ((size_t)2 * NN + 2 * (NN + 1) + (size_t)3 * NE) * 4;

    const int nbc = (NE + 255) / 256;   // 1954

    if (ws_size >= needed) {
        hipMemsetAsync(deg_s, 0, (size_t)2 * NN * sizeof(int), stream);
        count_w2r<<<nbc + 65, 256, 0, stream>>>(
            src, dst, deg_s, pos_s, deg_d, pos_d, W2, b2, W1, W2R, W1T);
        dgc_scan2<<<2, 1024, 0, stream>>>(deg_s, offs_s, deg_d, offs_d);
        scatter_tprep<<<nbc + 2048, 256, 0, stream>>>(
            src, pos_s, offs_s, eidx_s, x, W2R, T);
        edge_msg7<<<nbc, 256, 0, stream>>>(
            eidx_s, src, dst, ef, W1T, b1, T, offs_d, pos_d, msgbuf);
        gather_mean3<<<(NN * 4 + 255) / 256, 256, 0, stream>>>(
            msgbuf, offs_d, x, bias, out);
    } else {
        // round-2 fallback
        float* msg  = (float*)d_ws;
        int*   deg  = (int*)(msg + (size_t)NE * 16);
        int*   offs = deg + NN;
        int*   pos  = offs + NN + 1;
        int*   eidx = pos + NE;
        hipMemsetAsync(deg, 0, (size_t)NN * sizeof(int), stream);
        dgc_edge_csr<<<(NE + 255) / 256, 256, 0, stream>>>(
            x, ef, src, dst, W1, b1, W2, b2, msg, pos, deg);
        dgc_scan<<<1, 1024, 0, stream>>>(deg, offs, NN);
        dgc_scatter<<<(NE + 255) / 256, 256, 0, stream>>>(dst, pos, offs, eidx);
        dgc_gather<<<(NN * FOUT + 255) / 256, 256, 0, stream>>>(
            msg, offs, eidx, x, bias, out);
    }
}